// Round 5
// baseline (182.968 us; speedup 1.0000x reference)
//
#include <hip/hip_runtime.h>
#include <hip/hip_bf16.h>
#include <math.h>
#include <stdint.h>

#define Bd 2
#define Nd 1024
#define Dd 1024
#define Hh 16
#define EPSf 1e-6f
#define NPB 8

typedef short s8v __attribute__((ext_vector_type(8)));
typedef float f16v __attribute__((ext_vector_type(16)));
typedef float f4v __attribute__((ext_vector_type(4)));

#define MFMA32x32(A,B,C) __builtin_amdgcn_mfma_f32_32x32x16_bf16(A,B,C,0,0,0)

__device__ __forceinline__ void gl_lds16(const void* g, void* l) {
    __builtin_amdgcn_global_load_lds((const __attribute__((address_space(1))) unsigned int*)g,
                                     (__attribute__((address_space(3))) unsigned int*)l, 16, 0, 0);
}

__device__ __forceinline__ unsigned short bf16bits(float v) {
    __hip_bfloat16 h = __float2bfloat16(v);
    return *(unsigned short*)&h;
}
__device__ __forceinline__ float bf16rt(float v) {   // round-trip through bf16
    __hip_bfloat16 h = __float2bfloat16(v);
    return __bfloat162float(h);
}

// bank-conflict-free slot permutation: 8 consecutive lanes cover all 8 16B bank groups
__device__ __forceinline__ int posf(int l, int h) {
    return ((l & 3) << 1) | ((l >> 2) & 1) | (h << 3) | ((l >> 3) << 4);
}

// ---------------- Kernel 1: witness projections -> fragment-major bf16 witness rows ----------------
// global layout: wit[bh][kblk=n>>5][c=f>>4][posf(n&31,(f>>3)&1)*8 + (f&7)]  (ushort; 1KB/chunk, 20KB/kblk)
__global__ void witness_kernel(const float* __restrict__ x,
    const float* __restrict__ WE, const float* __restrict__ bE,
    const float* __restrict__ WS, const float* __restrict__ bS,
    const float* __restrict__ WH, const float* __restrict__ bH,
    const float* __restrict__ Wrff, const float* __restrict__ brff,
    unsigned short* __restrict__ wit, float* __restrict__ sqo,
    unsigned short* __restrict__ xb)
{
    const int e = threadIdx.x;           // 0..63
    int idx = blockIdx.x;
    const int NC = Nd / NPB;             // 128
    int nc = idx % NC;
    int h = (idx / NC) % Hh;
    int b = idx / (NC * Hh);
    int n0 = nc * NPB;
    size_t bh = (size_t)b * Hh + h;

    __shared__ float xs[NPB][64];
    __shared__ unsigned short wb[NPB][320];
    #pragma unroll
    for (int r = 0; r < NPB; r++) {
        float xv = x[((size_t)b * Nd + n0 + r) * Dd + h * 64 + e];
        xs[r][e] = xv;
        xb[((size_t)b * Nd + n0 + r) * Dd + h * 64 + e] = bf16bits(xv);
    }
    __syncthreads();

    size_t rowbase = (bh * Nd + n0);

    // ---- Euclidean (f = e) ----
    {
        float acc[NPB];
        #pragma unroll
        for (int r = 0; r < NPB; r++) acc[r] = 0.f;
        const float* Wp = WE + (size_t)h * 64 * 64 + e;
        for (int d = 0; d < 64; d++) {
            float w = Wp[(size_t)d * 64];
            #pragma unroll
            for (int r = 0; r < NPB; r++) acc[r] = fmaf(xs[r][d], w, acc[r]);
        }
        float bb = bE[h * 64 + e];
        #pragma unroll
        for (int r = 0; r < NPB; r++) {
            float v = acc[r] + bb;
            float vf = bf16rt(v);
            wb[r][e] = bf16bits(v);
            float s = vf * vf;
            for (int o = 32; o > 0; o >>= 1) s += __shfl_xor(s, o, 64);
            if (e == 0) sqo[(rowbase + r) * 4 + 0] = s;
        }
    }
    // ---- Spherical (f = 64+e) ----
    {
        float acc[NPB];
        #pragma unroll
        for (int r = 0; r < NPB; r++) acc[r] = 0.f;
        const float* Wp = WS + (size_t)h * 64 * 64 + e;
        for (int d = 0; d < 64; d++) {
            float w = Wp[(size_t)d * 64];
            #pragma unroll
            for (int r = 0; r < NPB; r++) acc[r] = fmaf(xs[r][d], w, acc[r]);
        }
        float bb = bS[h * 64 + e];
        #pragma unroll
        for (int r = 0; r < NPB; r++) {
            float v = acc[r] + bb;
            float s = v * v;
            for (int o = 32; o > 0; o >>= 1) s += __shfl_xor(s, o, 64);
            float nrm = sqrtf(s);
            wb[r][64 + e] = bf16bits(v / (nrm + EPSf));
        }
    }
    // ---- Hyperbolic (f = 128+e) ----
    {
        float acc[NPB];
        #pragma unroll
        for (int r = 0; r < NPB; r++) acc[r] = 0.f;
        const float* Wp = WH + (size_t)h * 64 * 64 + e;
        for (int d = 0; d < 64; d++) {
            float w = Wp[(size_t)d * 64];
            #pragma unroll
            for (int r = 0; r < NPB; r++) acc[r] = fmaf(xs[r][d], w, acc[r]);
        }
        float bb = bH[h * 64 + e];
        #pragma unroll
        for (int r = 0; r < NPB; r++) {
            float u = acc[r] + bb;
            float s = u * u;
            for (int o = 32; o > 0; o >>= 1) s += __shfl_xor(s, o, 64);
            float un = sqrtf(s);
            float sc = tanhf(un) / (un + EPSf);
            float w = sc * u;
            float wf = bf16rt(w);
            wb[r][128 + e] = bf16bits(w);
            float s2 = wf * wf;
            for (int o = 32; o > 0; o >>= 1) s2 += __shfl_xor(s2, o, 64);
            if (e == 0) {
                sqo[(rowbase + r) * 4 + 1] = s2;
                sqo[(rowbase + r) * 4 + 2] = 1.f - fminf(fmaxf(s2, 0.f), 1.f - 1e-5f);
            }
        }
    }
    // ---- RFF (f = 192+col) ----
    {
        float sF[NPB];
        #pragma unroll
        for (int r = 0; r < NPB; r++) sF[r] = 0.f;
        #pragma unroll
        for (int half = 0; half < 2; half++) {
            int col = e + 64 * half;
            float acc[NPB];
            #pragma unroll
            for (int r = 0; r < NPB; r++) acc[r] = 0.f;
            const float* Wp = Wrff + (size_t)h * 64 * 128 + col;
            for (int d = 0; d < 64; d++) {
                float w = Wp[(size_t)d * 128];
                #pragma unroll
                for (int r = 0; r < NPB; r++) acc[r] = fmaf(xs[r][d], w, acc[r]);
            }
            float bb = brff[h * 128 + col];
            #pragma unroll
            for (int r = 0; r < NPB; r++) {
                float zv = 0.125f * cosf(acc[r] + bb);
                float zf = bf16rt(zv);
                wb[r][192 + col] = bf16bits(zv);
                sF[r] += zf * zf;
            }
        }
        #pragma unroll
        for (int r = 0; r < NPB; r++) {
            float s = sF[r];
            for (int o = 32; o > 0; o >>= 1) s += __shfl_xor(s, o, 64);
            if (e == 0) sqo[(rowbase + r) * 4 + 3] = s;
        }
    }

    __syncthreads();
    // ---- coalesced 16B writeout of the 8 rows (320 slots) ----
    char* wgb = (char*)wit + bh * 655360 + (size_t)(n0 >> 5) * 20480;
    #pragma unroll
    for (int s = 0; s < 5; s++) {
        int slotid = s * 64 + e;
        int c = slotid >> 4, rem = slotid & 15, rr = rem >> 1, hh8 = rem & 1;
        int4 d = *(const int4*)((const char*)wb + rr * 640 + c * 32 + hh8 * 16);
        int l = (n0 & 31) + rr;
        *(int4*)(wgb + c * 1024 + posf(l, hh8) * 16) = d;
    }
}

// ---------------- convert f32 -> bf16 ----------------
__global__ void cvt_kernel(const float* __restrict__ src, unsigned short* __restrict__ dst, int n)
{
    int i = (blockIdx.x * blockDim.x + threadIdx.x) * 4;
    if (i < n) {
        float4 v = *(const float4*)(src + i);
        ushort4 o;
        o.x = bf16bits(v.x); o.y = bf16bits(v.y); o.z = bf16bits(v.z); o.w = bf16bits(v.w);
        *(ushort4*)(dst + i) = o;
    }
}

// ---------------- bf16 MFMA GEMM: C[M x 1024] = A[M x 1024] * W[1024 x 1024]^T + bias ----------------
// 64x64 tile, 256 threads (4 waves, each one 32x32), XOR-swizzled LDS, double-buffered.
// MODE 0: f32 row-major to outF.  MODE 1: bf16 fragment-major vt2 (coalesced via LDS buffer).
template<int MODE>
__global__ __launch_bounds__(256) void gemm_bf16_kernel(
    const unsigned short* __restrict__ A, const unsigned short* __restrict__ Bw,
    const float* __restrict__ bias, float* __restrict__ outF, unsigned short* __restrict__ outV)
{
    __shared__ __align__(16) char sm[32768];   // 2 x (At 8192 + Bt 8192)
    int tid = threadIdx.x, lane = tid & 63;
    int w = tid >> 6, wm = w >> 1, wn = w & 1;
    int h8 = lane >> 5, l31 = lane & 31;
    int i0 = blockIdx.y * 64, j0 = blockIdx.x * 64;
    const char* Ab = (const char*)A;
    const char* Bb = (const char*)Bw;

    f16v acc = {};

    auto stage = [&](int kt, int buf) {
        char* atb = sm + buf * 16384;
        char* btb = atb + 8192;
        #pragma unroll
        for (int j = 0; j < 2; j++) {
            int elem = j * 256 + tid;
            int row = elem >> 3, u = elem & 7;
            int so = (u * 16) ^ ((row & 7) << 4);
            gl_lds16(Ab + (size_t)(i0 + row) * 2048 + kt * 128 + so, atb + elem * 16);
            gl_lds16(Bb + (size_t)(j0 + row) * 2048 + kt * 128 + so, btb + elem * 16);
        }
    };

    stage(0, 0);
    __syncthreads();
    for (int kt = 0; kt < 16; kt++) {
        int buf = kt & 1;
        if (kt < 15) stage(kt + 1, buf ^ 1);
        const char* atb = sm + buf * 16384;
        const char* btb = atb + 8192;
        int swz = (l31 & 7) << 4;
        #pragma unroll
        for (int kk = 0; kk < 4; kk++) {
            s8v a = *(const s8v*)(atb + (wm * 32 + l31) * 128 + ((kk * 32 + h8 * 16) ^ swz));
            s8v bq = *(const s8v*)(btb + (wn * 32 + l31) * 128 + ((kk * 32 + h8 * 16) ^ swz));
            acc = MFMA32x32(a, bq, acc);
        }
        __syncthreads();
    }

    if (MODE == 0) {
        #pragma unroll
        for (int r = 0; r < 16; r++) {
            int rf = (r & 3) + 8 * (r >> 2) + 4 * h8;
            int grow = i0 + wm * 32 + rf;
            int gcol = j0 + wn * 32 + l31;
            outF[(size_t)grow * 1024 + gcol] = acc[r] + bias[gcol];
        }
    } else {
        unsigned short* vbuf = (unsigned short*)sm;  // [2][4][64][8] = 8KB
        int gcol = j0 + wn * 32 + l31;
        float bb = bias[gcol];
        #pragma unroll
        for (int r = 0; r < 16; r++) {
            int rf = (r & 3) + 8 * (r >> 2) + 4 * h8;   // token within 64-tile is wm*32+rf; kk = rf
            vbuf[wm * 2048 + ((rf >> 4) * 2 + wn) * 512 + posf(l31, (rf >> 3) & 1) * 8 + (rf & 7)]
                = bf16bits(acc[r] + bb);
        }
        __syncthreads();
        int bh2 = (i0 >> 10) * 16 + (j0 >> 6);
        int nloc = i0 & 1023;
        #pragma unroll
        for (int j = 0; j < 2; j++) {
            int sid = j * 256 + tid;
            int wm2 = sid >> 8, chunk = (sid >> 6) & 3, slot = sid & 63;
            int kblkg = ((nloc + wm2 * 32) >> 5);
            *(int4*)((char*)outV + (size_t)bh2 * 131072 + kblkg * 4096 + chunk * 1024 + slot * 16)
                = *(const int4*)((const char*)sm + sid * 16);
        }
    }
}

// ---------------- Kernel 3: MFMA distances + online softmax + MFMA PV ----------------
// 1024 blocks (XCD-swizzled), 4 waves = 4-way k-parity over one 32-q tile.
// K/V fragment-major from global (coalesced, L2-resident); Q in LDS (conflict-free posf layout);
// sq/mask in LDS; no barriers in main loop; rescale broadcast via shfl.
// LDS: [0:16384) sqAll (merge: O-slots 2x8K); [16384:20480) mkAll (merge: m,l); [20480:40960) Q
__global__ __launch_bounds__(256, 4) void attn_kernel(
    const unsigned short* __restrict__ wit, const float* __restrict__ sqb,
    const unsigned short* __restrict__ vt, const int* __restrict__ mask,
    const float* __restrict__ al_, const float* __restrict__ be_,
    const float* __restrict__ ga_, const float* __restrict__ de_,
    const float* __restrict__ tp_,
    __hip_bfloat16* __restrict__ aout)
{
    __shared__ __align__(16) char sm[40960];
    int tid = threadIdx.x, lane = tid & 63;
    int par = tid >> 6;                       // 0..3: k-parity
    int h8 = lane >> 5, l31 = lane & 31, h4 = h8 * 4;

    int bid = blockIdx.x;
    int xcd = bid & 7, slot = bid >> 3;       // slot 0..127
    int bh = (xcd << 2) | (slot >> 5);        // 0..31
    int qt = slot & 31;
    int bz = bh >> 4, hh = bh & 15;
    int q0 = qt * 32;

    const char* witb = (const char*)wit + (size_t)bh * 655360;
    const char* vtb = (const char*)vt + (size_t)bh * 131072;

    float* sqAll = (float*)sm;                       // [1024][4]
    const int* mkAll = (const int*)(sm + 16384);     // [1024]
    char* qlds = sm + 20480;                         // 20KB Q tile (fragment-major)

    // ---- one-time stage: sq (16KB), mask (4KB), Q tile (20KB) ----
    #pragma unroll
    for (int j = 0; j < 4; j++) {
        int blk = par * 4 + j;
        gl_lds16((const char*)sqb + (size_t)bh * 16384 + blk * 1024 + lane * 16,
                 sm + blk * 1024);
    }
    gl_lds16((const char*)(mask + (size_t)bz * Nd) + par * 1024 + lane * 16,
             sm + 16384 + par * 1024);
    #pragma unroll
    for (int j = 0; j < 5; j++) {
        int ch = par * 5 + j;
        gl_lds16(witb + (size_t)qt * 20480 + ch * 1024 + lane * 16,
                 qlds + ch * 1024);
    }

    int laneoff = posf(l31, h8) * 16;

    f4v sqq = *(const f4v*)(sqb + ((size_t)bh * Nd + q0 + l31) * 4);
    const float LOG2E = 1.4426950408889634f;
    const float LN2 = 0.6931471805599453f;
    float itmp2 = LOG2E / tp_[hh];
    float al2 = -al_[hh] * itmp2;
    float be2 = -be_[hh] * itmp2;
    float de2 = -de_[hh] * itmp2;
    float gl2 = -ga_[hh] * itmp2 * LN2;       // dH computed as log2 -> fold ln2
    float sqqxE = sqq.x + EPSf, sqqwE = sqq.w + EPSf;
    float sqqy = sqq.y, sqqz = sqq.z;

    float m_run = -INFINITY, l_run = 0.f;
    f16v o0 = {}, o1 = {};

    __syncthreads();   // staging complete

    for (int it = 0; it < 8; it++) {
        int kblk = it * 4 + par;
        int k0 = kblk * 32;
        const char* kp = witb + (size_t)kblk * 20480 + laneoff;

        // ---- grams: D = K . Q^T (row=k, col=q) ----
        __builtin_amdgcn_s_setprio(1);
        f16v aE = {}, aS = {}, aH = {}, aF = {};
        #pragma unroll
        for (int c = 0; c < 20; c++) {
            s8v a = *(const s8v*)(kp + c * 1024);
            s8v q = *(const s8v*)(qlds + c * 1024 + laneoff);
            if (c < 4)       aE = MFMA32x32(a, q, aE);
            else if (c < 8)  aS = MFMA32x32(a, q, aS);
            else if (c < 12) aH = MFMA32x32(a, q, aH);
            else             aF = MFMA32x32(a, q, aF);
        }
        __builtin_amdgcn_s_setprio(0);

        // ---- distances -> logits (log2 domain) ----
        float p[16];
        #pragma unroll
        for (int r = 0; r < 16; r++) {
            int kr = (r & 3) + 8 * (r >> 2) + h4;
            const float4 sk = *(const float4*)(sqAll + (size_t)(k0 + kr) * 4);
            float sE = fmaxf(fmaf(-2.f, aE[r], sqqxE + sk.x), EPSf);
            float dE = __builtin_amdgcn_sqrtf(sE);
            float cv = aS[r];
            float ax = fminf(fabsf(cv), 1.f - EPSf);
            float sq1 = __builtin_amdgcn_sqrtf(1.f - ax);
            float pa = sq1 * fmaf(ax, fmaf(ax, fmaf(ax, -0.0187293f, 0.0742610f), -0.2121144f), 1.5707288f);
            float dS = (cv < 0.f) ? (3.14159265f - pa) : pa;
            float d2 = fmaxf(fmaf(-2.f, aH[r], sqqy + sk.y), 0.f);
            float den = fmaf(sqqz, sk.z, EPSf);
            float arx = fmaxf(fmaf(d2 + d2, __builtin_amdgcn_rcpf(den), 1.f), 1.f + EPSf);
            float sh = __builtin_amdgcn_sqrtf(fmaf(arx, arx, -1.f));
            float lH = log2f(arx + sh);
            float sF = fmaxf(fmaf(-2.f, aF[r], sqqwE + sk.w), EPSf);
            float dF = __builtin_amdgcn_sqrtf(sF);
            float lg = fmaf(al2, dE, fmaf(be2, dS, fmaf(de2, dF, gl2 * lH)));
            p[r] = (mkAll[k0 + kr] > 0) ? lg : -1e9f;
        }

        // ---- online softmax with defer-max (THR = 8 in log2 units) ----
        float mt = p[0];
        #pragma unroll
        for (int r = 1; r < 16; r++) mt = fmaxf(mt, p[r]);
        mt = fmaxf(mt, __shfl_xor(mt, 32, 64));
        if (!__all(mt <= m_run + 8.f)) {
            float mnew = fmaxf(m_run, mt);
            float sc = exp2f(m_run - mnew);
            l_run *= sc;
            m_run = mnew;
            #pragma unroll
            for (int r = 0; r < 16; r++) {
                float s = __shfl(sc, (r & 3) + 8 * (r >> 2) + h4, 64);
                o0[r] *= s; o1[r] *= s;
            }
        }
        float ps = 0.f;
        #pragma unroll
        for (int r = 0; r < 16; r++) { p[r] = exp2f(p[r] - m_run); ps += p[r]; }
        ps += __shfl_xor(ps, 32, 64);
        l_run += ps;

        // ---- P relayout: f32 (D-layout) -> bf16 A-frags via cvt_pk + permlane32_swap ----
        unsigned int w0, w1, w2, w3, y0, y1, y2, y3;
        asm("v_cvt_pk_bf16_f32 %0, %1, %2" : "=v"(w0) : "v"(p[0]), "v"(p[1]));
        asm("v_cvt_pk_bf16_f32 %0, %1, %2" : "=v"(w1) : "v"(p[2]), "v"(p[3]));
        asm("v_cvt_pk_bf16_f32 %0, %1, %2" : "=v"(w2) : "v"(p[4]), "v"(p[5]));
        asm("v_cvt_pk_bf16_f32 %0, %1, %2" : "=v"(w3) : "v"(p[6]), "v"(p[7]));
        asm("v_cvt_pk_bf16_f32 %0, %1, %2" : "=v"(y0) : "v"(p[8]), "v"(p[9]));
        asm("v_cvt_pk_bf16_f32 %0, %1, %2" : "=v"(y1) : "v"(p[10]), "v"(p[11]));
        asm("v_cvt_pk_bf16_f32 %0, %1, %2" : "=v"(y2) : "v"(p[12]), "v"(p[13]));
        asm("v_cvt_pk_bf16_f32 %0, %1, %2" : "=v"(y3) : "v"(p[14]), "v"(p[15]));
        asm volatile("v_permlane32_swap_b32 %0, %1" : "+v"(w0), "+v"(w2));
        asm volatile("v_permlane32_swap_b32 %0, %1" : "+v"(w1), "+v"(w3));
        asm volatile("v_permlane32_swap_b32 %0, %1" : "+v"(y0), "+v"(y2));
        asm volatile("v_permlane32_swap_b32 %0, %1" : "+v"(y1), "+v"(y3));
        int4 t1; t1.x = (int)w0; t1.y = (int)w1; t1.z = (int)w2; t1.w = (int)w3;
        int4 t2; t2.x = (int)y0; t2.y = (int)y1; t2.z = (int)y2; t2.w = (int)y3;
        s8v A1 = *(s8v*)&t1;
        s8v A2 = *(s8v*)&t2;

        // ---- PV: O += P . V   (V frags direct from global, fragment-major) ----
        const char* vp = vtb + (size_t)kblk * 4096 + laneoff;
        s8v b00 = *(const s8v*)(vp);             // k 0..15,  d 0..31
        s8v b01 = *(const s8v*)(vp + 1024);      // k 0..15,  d 32..63
        s8v b10 = *(const s8v*)(vp + 2048);      // k 16..31, d 0..31
        s8v b11 = *(const s8v*)(vp + 3072);      // k 16..31, d 32..63
        __builtin_amdgcn_s_setprio(1);
        o0 = MFMA32x32(A1, b00, o0);
        o0 = MFMA32x32(A2, b10, o0);
        o1 = MFMA32x32(A1, b01, o1);
        o1 = MFMA32x32(A2, b11, o1);
        __builtin_amdgcn_s_setprio(0);
    }

    // ---- merge 4 parity partials (tree: {2,3}->{0,1}, then 1->0) ----
    float* slotO0 = (float*)sm;                 // 32q x 64d
    float* slotO1 = (float*)(sm + 8192);
    float* slotM0 = (float*)(sm + 16384);       // m[32], l[32]
    float* slotM1 = (float*)(sm + 16896);

    __syncthreads();
    if (par >= 2) {
        float* so = (par == 2) ? slotO0 : slotO1;
        float* sM = (par == 2) ? slotM0 : slotM1;
        #pragma unroll
        for (int r = 0; r < 16; r++) {
            int qr = (r & 3) + 8 * (r >> 2) + h4;
            so[qr * 64 + l31] = o0[r];
            so[qr * 64 + 32 + l31] = o1[r];
        }
        if (lane < 32) { sM[lane] = m_run; sM[32 + lane] = l_run; }
    }
    __syncthreads();
    if (par < 2) {
        float* so = (par == 0) ? slotO0 : slotO1;
        float* sM = (par == 0) ? slotM0 : slotM1;
        float m2 = sM[l31], l2 = sM[32 + l31];
        float M = fmaxf(m_run, m2);
        float s1 = exp2f(m_run - M), s2 = exp2f(m2 - M);
        l_run = l_run * s1 + l2 * s2;
        m_run = M;
        #pragma unroll
        for (int r = 0; r < 16; r++) {
            int qr = (r & 3) + 8 * (r >> 2) + h4;
            float a = __shfl(s1, qr, 64), b = __shfl(s2, qr, 64);
            o0[r] = o0[r] * a + so[qr * 64 + l31] * b;
            o1[r] = o1[r] * a + so[qr * 64 + 32 + l31] * b;
        }
    }
    __syncthreads();
    if (par == 1) {
        #pragma unroll
        for (int r = 0; r < 16; r++) {
            int qr = (r & 3) + 8 * (r >> 2) + h4;
            slotO0[qr * 64 + l31] = o0[r];
            slotO0[qr * 64 + 32 + l31] = o1[r];
        }
        if (lane < 32) { slotM0[lane] = m_run; slotM0[32 + lane] = l_run; }
    }
    __syncthreads();
    if (par == 0) {
        float m2 = slotM0[l31], l2 = slotM0[32 + l31];
        float M = fmaxf(m_run, m2);
        float s1 = exp2f(m_run - M), s2 = exp2f(m2 - M);
        float lt = l_run * s1 + l2 * s2;
        float inv = 1.f / lt;
        float a0 = s1 * inv, b0 = s2 * inv;
        #pragma unroll
        for (int r = 0; r < 16; r++) {
            int qr = (r & 3) + 8 * (r >> 2) + h4;
            float a = __shfl(a0, qr, 64), b = __shfl(b0, qr, 64);
            float r0 = o0[r] * a + slotO0[qr * 64 + l31] * b;
            float r1 = o1[r] * a + slotO0[qr * 64 + 32 + l31] * b;
            size_t row = (size_t)bz * Nd + q0 + qr;
            aout[row * Dd + hh * 64 + l31] = __float2bfloat16(r0);
            aout[row * Dd + hh * 64 + 32 + l31] = __float2bfloat16(r1);
        }
    }
}

extern "C" void kernel_launch(void* const* d_in, const int* in_sizes, int n_in,
                              void* d_out, int out_size, void* d_ws, size_t ws_size,
                              hipStream_t stream) {
    const float* x    = (const float*)d_in[0];
    const int*   mask = (const int*)d_in[1];
    const float* WE   = (const float*)d_in[2];
    const float* bE   = (const float*)d_in[3];
    const float* WS   = (const float*)d_in[4];
    const float* bS   = (const float*)d_in[5];
    const float* WH   = (const float*)d_in[6];
    const float* bH   = (const float*)d_in[7];
    const float* Wrff = (const float*)d_in[8];
    const float* brff = (const float*)d_in[9];
    const float* alpha = (const float*)d_in[10];
    const float* beta  = (const float*)d_in[11];
    const float* gamma_ = (const float*)d_in[12];
    const float* delta = (const float*)d_in[13];
    const float* temperature = (const float*)d_in[14];
    const float* Wv = (const float*)d_in[15];
    const float* bv = (const float*)d_in[16];
    const float* Wo = (const float*)d_in[17];
    const float* bo = (const float*)d_in[18];

    char* ws = (char*)d_ws;
    unsigned short* wit = (unsigned short*)ws;             // 32768*320*2 = 20971520
    float* sq  = (float*)(ws + 20971520);                  // 32768*4*4   = 524288
    unsigned short* xb  = (unsigned short*)(ws + 21495808);// 2M*2        = 4194304
    unsigned short* wvb = (unsigned short*)(ws + 25690112);// 1M*2        = 2097152
    unsigned short* wob = (unsigned short*)(ws + 27787264);// 1M*2        = 2097152
    unsigned short* vt  = (unsigned short*)(ws + 29884416);// 2M*2        = 4194304
    __hip_bfloat16* aout = (__hip_bfloat16*)(ws + 34078720); // 2M*2      = 4194304

    witness_kernel<<<dim3(Bd * Hh * (Nd / NPB)), 64, 0, stream>>>(
        x, WE, bE, WS, bS, WH, bH, Wrff, brff, wit, sq, xb);

    cvt_kernel<<<dim3(1024), 256, 0, stream>>>(Wv, wvb, 1 << 20);
    cvt_kernel<<<dim3(1024), 256, 0, stream>>>(Wo, wob, 1 << 20);

    gemm_bf16_kernel<1><<<dim3(16, 32), 256, 0, stream>>>(xb, wvb, bv, nullptr, vt);

    attn_kernel<<<dim3(1024), 256, 0, stream>>>(
        wit, sq, vt, mask, alpha, beta, gamma_, delta, temperature, aout);

    gemm_bf16_kernel<0><<<dim3(16, 32), 256, 0, stream>>>(
        (const unsigned short*)aout, wob, bo, (float*)d_out, nullptr);
}

// Round 6
// 160.624 us; speedup vs baseline: 1.1391x; 1.1391x over previous
//
#include <hip/hip_runtime.h>
#include <hip/hip_bf16.h>
#include <math.h>
#include <stdint.h>

#define Bd 2
#define Nd 1024
#define Dd 1024
#define Hh 16
#define EPSf 1e-6f
#define NPB 8

typedef short s8v __attribute__((ext_vector_type(8)));
typedef float f16v __attribute__((ext_vector_type(16)));
typedef float f4v __attribute__((ext_vector_type(4)));

#define MFMA32x32(A,B,C) __builtin_amdgcn_mfma_f32_32x32x16_bf16(A,B,C,0,0,0)

__device__ __forceinline__ void gl_lds16(const void* g, void* l) {
    __builtin_amdgcn_global_load_lds((const __attribute__((address_space(1))) unsigned int*)g,
                                     (__attribute__((address_space(3))) unsigned int*)l, 16, 0, 0);
}

__device__ __forceinline__ unsigned short bf16bits(float v) {
    __hip_bfloat16 h = __float2bfloat16(v);
    return *(unsigned short*)&h;
}
__device__ __forceinline__ float bf16rt(float v) {   // round-trip through bf16
    __hip_bfloat16 h = __float2bfloat16(v);
    return __bfloat162float(h);
}

// bank-conflict-free slot permutation: 8 consecutive lanes cover all 8 16B bank groups
__device__ __forceinline__ int posf(int l, int h) {
    return ((l & 3) << 1) | ((l >> 2) & 1) | (h << 3) | ((l >> 3) << 4);
}

// ---------------- Kernel 1: witness projections -> fragment-major bf16 witness rows ----------------
// global layout: wit[bh][kblk=n>>5][c=f>>4][posf(n&31,(f>>3)&1)*8 + (f&7)]  (ushort; 1KB/chunk, 20KB/kblk)
__global__ void witness_kernel(const float* __restrict__ x,
    const float* __restrict__ WE, const float* __restrict__ bE,
    const float* __restrict__ WS, const float* __restrict__ bS,
    const float* __restrict__ WH, const float* __restrict__ bH,
    const float* __restrict__ Wrff, const float* __restrict__ brff,
    unsigned short* __restrict__ wit, float* __restrict__ sqo,
    unsigned short* __restrict__ xb)
{
    const int e = threadIdx.x;           // 0..63
    int idx = blockIdx.x;
    const int NC = Nd / NPB;             // 128
    int nc = idx % NC;
    int h = (idx / NC) % Hh;
    int b = idx / (NC * Hh);
    int n0 = nc * NPB;
    size_t bh = (size_t)b * Hh + h;

    __shared__ float xs[NPB][64];
    __shared__ unsigned short wb[NPB][320];
    #pragma unroll
    for (int r = 0; r < NPB; r++) {
        float xv = x[((size_t)b * Nd + n0 + r) * Dd + h * 64 + e];
        xs[r][e] = xv;
        xb[((size_t)b * Nd + n0 + r) * Dd + h * 64 + e] = bf16bits(xv);
    }
    __syncthreads();

    size_t rowbase = (bh * Nd + n0);

    // ---- Euclidean (f = e) ----
    {
        float acc[NPB];
        #pragma unroll
        for (int r = 0; r < NPB; r++) acc[r] = 0.f;
        const float* Wp = WE + (size_t)h * 64 * 64 + e;
        for (int d = 0; d < 64; d++) {
            float w = Wp[(size_t)d * 64];
            #pragma unroll
            for (int r = 0; r < NPB; r++) acc[r] = fmaf(xs[r][d], w, acc[r]);
        }
        float bb = bE[h * 64 + e];
        #pragma unroll
        for (int r = 0; r < NPB; r++) {
            float v = acc[r] + bb;
            float vf = bf16rt(v);
            wb[r][e] = bf16bits(v);
            float s = vf * vf;
            for (int o = 32; o > 0; o >>= 1) s += __shfl_xor(s, o, 64);
            if (e == 0) sqo[(rowbase + r) * 4 + 0] = s;
        }
    }
    // ---- Spherical (f = 64+e) ----
    {
        float acc[NPB];
        #pragma unroll
        for (int r = 0; r < NPB; r++) acc[r] = 0.f;
        const float* Wp = WS + (size_t)h * 64 * 64 + e;
        for (int d = 0; d < 64; d++) {
            float w = Wp[(size_t)d * 64];
            #pragma unroll
            for (int r = 0; r < NPB; r++) acc[r] = fmaf(xs[r][d], w, acc[r]);
        }
        float bb = bS[h * 64 + e];
        #pragma unroll
        for (int r = 0; r < NPB; r++) {
            float v = acc[r] + bb;
            float s = v * v;
            for (int o = 32; o > 0; o >>= 1) s += __shfl_xor(s, o, 64);
            float nrm = sqrtf(s);
            wb[r][64 + e] = bf16bits(v / (nrm + EPSf));
        }
    }
    // ---- Hyperbolic (f = 128+e) ----
    {
        float acc[NPB];
        #pragma unroll
        for (int r = 0; r < NPB; r++) acc[r] = 0.f;
        const float* Wp = WH + (size_t)h * 64 * 64 + e;
        for (int d = 0; d < 64; d++) {
            float w = Wp[(size_t)d * 64];
            #pragma unroll
            for (int r = 0; r < NPB; r++) acc[r] = fmaf(xs[r][d], w, acc[r]);
        }
        float bb = bH[h * 64 + e];
        #pragma unroll
        for (int r = 0; r < NPB; r++) {
            float u = acc[r] + bb;
            float s = u * u;
            for (int o = 32; o > 0; o >>= 1) s += __shfl_xor(s, o, 64);
            float un = sqrtf(s);
            float sc = tanhf(un) / (un + EPSf);
            float w = sc * u;
            float wf = bf16rt(w);
            wb[r][128 + e] = bf16bits(w);
            float s2 = wf * wf;
            for (int o = 32; o > 0; o >>= 1) s2 += __shfl_xor(s2, o, 64);
            if (e == 0) {
                sqo[(rowbase + r) * 4 + 1] = s2;
                sqo[(rowbase + r) * 4 + 2] = 1.f - fminf(fmaxf(s2, 0.f), 1.f - 1e-5f);
            }
        }
    }
    // ---- RFF (f = 192+col) ----
    {
        float sF[NPB];
        #pragma unroll
        for (int r = 0; r < NPB; r++) sF[r] = 0.f;
        #pragma unroll
        for (int half = 0; half < 2; half++) {
            int col = e + 64 * half;
            float acc[NPB];
            #pragma unroll
            for (int r = 0; r < NPB; r++) acc[r] = 0.f;
            const float* Wp = Wrff + (size_t)h * 64 * 128 + col;
            for (int d = 0; d < 64; d++) {
                float w = Wp[(size_t)d * 128];
                #pragma unroll
                for (int r = 0; r < NPB; r++) acc[r] = fmaf(xs[r][d], w, acc[r]);
            }
            float bb = brff[h * 128 + col];
            #pragma unroll
            for (int r = 0; r < NPB; r++) {
                float zv = 0.125f * cosf(acc[r] + bb);
                float zf = bf16rt(zv);
                wb[r][192 + col] = bf16bits(zv);
                sF[r] += zf * zf;
            }
        }
        #pragma unroll
        for (int r = 0; r < NPB; r++) {
            float s = sF[r];
            for (int o = 32; o > 0; o >>= 1) s += __shfl_xor(s, o, 64);
            if (e == 0) sqo[(rowbase + r) * 4 + 3] = s;
        }
    }

    __syncthreads();
    // ---- coalesced 16B writeout of the 8 rows (320 slots) ----
    char* wgb = (char*)wit + bh * 655360 + (size_t)(n0 >> 5) * 20480;
    #pragma unroll
    for (int s = 0; s < 5; s++) {
        int slotid = s * 64 + e;
        int c = slotid >> 4, rem = slotid & 15, rr = rem >> 1, hh8 = rem & 1;
        int4 d = *(const int4*)((const char*)wb + rr * 640 + c * 32 + hh8 * 16);
        int l = (n0 & 31) + rr;
        *(int4*)(wgb + c * 1024 + posf(l, hh8) * 16) = d;
    }
}

// ---------------- convert f32 -> bf16 ----------------
__global__ void cvt_kernel(const float* __restrict__ src, unsigned short* __restrict__ dst, int n)
{
    int i = (blockIdx.x * blockDim.x + threadIdx.x) * 4;
    if (i < n) {
        float4 v = *(const float4*)(src + i);
        ushort4 o;
        o.x = bf16bits(v.x); o.y = bf16bits(v.y); o.z = bf16bits(v.z); o.w = bf16bits(v.w);
        *(ushort4*)(dst + i) = o;
    }
}

// ---------------- bf16 MFMA GEMM: C[M x 1024] = A[M x 1024] * W[1024 x 1024]^T + bias ----------------
// 64x64 tile, 256 threads (4 waves, each one 32x32), XOR-swizzled LDS, double-buffered.
// MODE 0: f32 row-major to outF.  MODE 1: bf16 fragment-major vt2 (coalesced via LDS buffer).
template<int MODE>
__global__ __launch_bounds__(256) void gemm_bf16_kernel(
    const unsigned short* __restrict__ A, const unsigned short* __restrict__ Bw,
    const float* __restrict__ bias, float* __restrict__ outF, unsigned short* __restrict__ outV)
{
    __shared__ __align__(16) char sm[32768];   // 2 x (At 8192 + Bt 8192)
    int tid = threadIdx.x, lane = tid & 63;
    int w = tid >> 6, wm = w >> 1, wn = w & 1;
    int h8 = lane >> 5, l31 = lane & 31;
    int i0 = blockIdx.y * 64, j0 = blockIdx.x * 64;
    const char* Ab = (const char*)A;
    const char* Bb = (const char*)Bw;

    f16v acc = {};

    auto stage = [&](int kt, int buf) {
        char* atb = sm + buf * 16384;
        char* btb = atb + 8192;
        #pragma unroll
        for (int j = 0; j < 2; j++) {
            int elem = j * 256 + tid;
            int row = elem >> 3, u = elem & 7;
            int so = (u * 16) ^ ((row & 7) << 4);
            gl_lds16(Ab + (size_t)(i0 + row) * 2048 + kt * 128 + so, atb + elem * 16);
            gl_lds16(Bb + (size_t)(j0 + row) * 2048 + kt * 128 + so, btb + elem * 16);
        }
    };

    stage(0, 0);
    __syncthreads();
    for (int kt = 0; kt < 16; kt++) {
        int buf = kt & 1;
        if (kt < 15) stage(kt + 1, buf ^ 1);
        const char* atb = sm + buf * 16384;
        const char* btb = atb + 8192;
        int swz = (l31 & 7) << 4;
        #pragma unroll
        for (int kk = 0; kk < 4; kk++) {
            s8v a = *(const s8v*)(atb + (wm * 32 + l31) * 128 + ((kk * 32 + h8 * 16) ^ swz));
            s8v bq = *(const s8v*)(btb + (wn * 32 + l31) * 128 + ((kk * 32 + h8 * 16) ^ swz));
            acc = MFMA32x32(a, bq, acc);
        }
        __syncthreads();
    }

    if (MODE == 0) {
        #pragma unroll
        for (int r = 0; r < 16; r++) {
            int rf = (r & 3) + 8 * (r >> 2) + 4 * h8;
            int grow = i0 + wm * 32 + rf;
            int gcol = j0 + wn * 32 + l31;
            outF[(size_t)grow * 1024 + gcol] = acc[r] + bias[gcol];
        }
    } else {
        unsigned short* vbuf = (unsigned short*)sm;  // [2][4][64][8] = 8KB
        int gcol = j0 + wn * 32 + l31;
        float bb = bias[gcol];
        #pragma unroll
        for (int r = 0; r < 16; r++) {
            int rf = (r & 3) + 8 * (r >> 2) + 4 * h8;   // token within 64-tile is wm*32+rf; kk = rf
            vbuf[wm * 2048 + ((rf >> 4) * 2 + wn) * 512 + posf(l31, (rf >> 3) & 1) * 8 + (rf & 7)]
                = bf16bits(acc[r] + bb);
        }
        __syncthreads();
        int bh2 = (i0 >> 10) * 16 + (j0 >> 6);
        int nloc = i0 & 1023;
        #pragma unroll
        for (int j = 0; j < 2; j++) {
            int sid = j * 256 + tid;
            int wm2 = sid >> 8, chunk = (sid >> 6) & 3, slot = sid & 63;
            int kblkg = ((nloc + wm2 * 32) >> 5);
            *(int4*)((char*)outV + (size_t)bh2 * 131072 + kblkg * 4096 + chunk * 1024 + slot * 16)
                = *(const int4*)((const char*)sm + sid * 16);
        }
    }
}

// ---------------- Kernel 3: MFMA distances + online softmax + MFMA PV ----------------
// 1024 blocks (XCD-swizzled), 4 waves = 4-way k-parity over one 32-q tile.
// 2-PASS gram (E,S -> partial logits, then H,F -> final) to halve accumulator live set
// so 4 blocks/CU fit without spills under __launch_bounds__(256,4).
// K/V fragment-major from global (coalesced, L2-resident); Q in LDS (posf layout);
// sq/mask in LDS; no barriers in main loop; rescale broadcast via shfl.
// LDS: [0:16384) sqAll (merge: O-slots 2x8K); [16384:20480) mkAll (merge: m,l); [20480:40960) Q
__global__ __launch_bounds__(256, 4) void attn_kernel(
    const unsigned short* __restrict__ wit, const float* __restrict__ sqb,
    const unsigned short* __restrict__ vt, const int* __restrict__ mask,
    const float* __restrict__ al_, const float* __restrict__ be_,
    const float* __restrict__ ga_, const float* __restrict__ de_,
    const float* __restrict__ tp_,
    __hip_bfloat16* __restrict__ aout)
{
    __shared__ __align__(16) char sm[40960];
    int tid = threadIdx.x, lane = tid & 63;
    int par = tid >> 6;                       // 0..3: k-parity
    int h8 = lane >> 5, l31 = lane & 31, h4 = h8 * 4;

    int bid = blockIdx.x;
    int xcd = bid & 7, slot = bid >> 3;       // slot 0..127
    int bh = (xcd << 2) | (slot >> 5);        // 0..31
    int qt = slot & 31;
    int bz = bh >> 4, hh = bh & 15;
    int q0 = qt * 32;

    const char* witb = (const char*)wit + (size_t)bh * 655360;
    const char* vtb = (const char*)vt + (size_t)bh * 131072;

    float* sqAll = (float*)sm;                       // [1024][4]
    const int* mkAll = (const int*)(sm + 16384);     // [1024]
    char* qlds = sm + 20480;                         // 20KB Q tile (fragment-major)

    // ---- one-time stage: sq (16KB), mask (4KB), Q tile (20KB) ----
    #pragma unroll
    for (int j = 0; j < 4; j++) {
        int blk = par * 4 + j;
        gl_lds16((const char*)sqb + (size_t)bh * 16384 + blk * 1024 + lane * 16,
                 sm + blk * 1024);
    }
    gl_lds16((const char*)(mask + (size_t)bz * Nd) + par * 1024 + lane * 16,
             sm + 16384 + par * 1024);
    #pragma unroll
    for (int j = 0; j < 5; j++) {
        int ch = par * 5 + j;
        gl_lds16(witb + (size_t)qt * 20480 + ch * 1024 + lane * 16,
                 qlds + ch * 1024);
    }

    int laneoff = posf(l31, h8) * 16;

    f4v sqq = *(const f4v*)(sqb + ((size_t)bh * Nd + q0 + l31) * 4);
    const float LOG2E = 1.4426950408889634f;
    const float LN2 = 0.6931471805599453f;
    float itmp2 = LOG2E / tp_[hh];
    float al2 = -al_[hh] * itmp2;
    float be2 = -be_[hh] * itmp2;
    float de2 = -de_[hh] * itmp2;
    float gl2 = -ga_[hh] * itmp2 * LN2;       // dH computed as log2 -> fold ln2
    float sqqxE = sqq.x + EPSf, sqqwE = sqq.w + EPSf;
    float sqqy = sqq.y, sqqz = sqq.z;

    float m_run = -INFINITY, l_run = 0.f;
    f16v o0 = {}, o1 = {};

    __syncthreads();   // staging complete

    for (int it = 0; it < 8; it++) {
        int kblk = it * 4 + par;
        int k0 = kblk * 32;
        const char* kp = witb + (size_t)kblk * 20480 + laneoff;
        float p[16];

        // ---- PASS 1: grams E,S -> partial logits ----
        {
            __builtin_amdgcn_s_setprio(1);
            f16v aE = {}, aS = {};
            #pragma unroll
            for (int c = 0; c < 8; c++) {
                s8v a = *(const s8v*)(kp + c * 1024);
                s8v q = *(const s8v*)(qlds + c * 1024 + laneoff);
                if (c < 4) aE = MFMA32x32(a, q, aE);
                else       aS = MFMA32x32(a, q, aS);
            }
            __builtin_amdgcn_s_setprio(0);
            #pragma unroll
            for (int r = 0; r < 16; r++) {
                int kr = (r & 3) + 8 * (r >> 2) + h4;
                float skx = sqAll[(size_t)(k0 + kr) * 4];
                float sE = fmaxf(fmaf(-2.f, aE[r], sqqxE + skx), EPSf);
                float dE = __builtin_amdgcn_sqrtf(sE);
                float cv = aS[r];
                float ax = fminf(fabsf(cv), 1.f - EPSf);
                float sq1 = __builtin_amdgcn_sqrtf(1.f - ax);
                float pa = sq1 * fmaf(ax, fmaf(ax, fmaf(ax, -0.0187293f, 0.0742610f), -0.2121144f), 1.5707288f);
                float dS = (cv < 0.f) ? (3.14159265f - pa) : pa;
                p[r] = fmaf(al2, dE, be2 * dS);
            }
        }

        // ---- PASS 2: grams H,F -> final logits ----
        {
            __builtin_amdgcn_s_setprio(1);
            f16v aH = {}, aF = {};
            #pragma unroll
            for (int c = 8; c < 20; c++) {
                s8v a = *(const s8v*)(kp + c * 1024);
                s8v q = *(const s8v*)(qlds + c * 1024 + laneoff);
                if (c < 12) aH = MFMA32x32(a, q, aH);
                else        aF = MFMA32x32(a, q, aF);
            }
            __builtin_amdgcn_s_setprio(0);
            #pragma unroll
            for (int r = 0; r < 16; r++) {
                int kr = (r & 3) + 8 * (r >> 2) + h4;
                const float4 sk = *(const float4*)(sqAll + (size_t)(k0 + kr) * 4);
                float d2 = fmaxf(fmaf(-2.f, aH[r], sqqy + sk.y), 0.f);
                float den = fmaf(sqqz, sk.z, EPSf);
                float arx = fmaxf(fmaf(d2 + d2, __builtin_amdgcn_rcpf(den), 1.f), 1.f + EPSf);
                float sh = __builtin_amdgcn_sqrtf(fmaf(arx, arx, -1.f));
                float lH = log2f(arx + sh);
                float sF = fmaxf(fmaf(-2.f, aF[r], sqqwE + sk.w), EPSf);
                float dF = __builtin_amdgcn_sqrtf(sF);
                float lg = fmaf(de2, dF, fmaf(gl2, lH, p[r]));
                p[r] = (mkAll[k0 + kr] > 0) ? lg : -1e9f;
            }
        }

        // ---- online softmax with defer-max (THR = 8 in log2 units) ----
        float mt = p[0];
        #pragma unroll
        for (int r = 1; r < 16; r++) mt = fmaxf(mt, p[r]);
        mt = fmaxf(mt, __shfl_xor(mt, 32, 64));
        if (!__all(mt <= m_run + 8.f)) {
            float mnew = fmaxf(m_run, mt);
            float sc = exp2f(m_run - mnew);
            l_run *= sc;
            m_run = mnew;
            #pragma unroll
            for (int r = 0; r < 16; r++) {
                float s = __shfl(sc, (r & 3) + 8 * (r >> 2) + h4, 64);
                o0[r] *= s; o1[r] *= s;
            }
        }
        float ps = 0.f;
        #pragma unroll
        for (int r = 0; r < 16; r++) { p[r] = exp2f(p[r] - m_run); ps += p[r]; }
        ps += __shfl_xor(ps, 32, 64);
        l_run += ps;

        // ---- P relayout: f32 (D-layout) -> bf16 A-frags via cvt_pk + permlane32_swap ----
        unsigned int w0, w1, w2, w3, y0, y1, y2, y3;
        asm("v_cvt_pk_bf16_f32 %0, %1, %2" : "=v"(w0) : "v"(p[0]), "v"(p[1]));
        asm("v_cvt_pk_bf16_f32 %0, %1, %2" : "=v"(w1) : "v"(p[2]), "v"(p[3]));
        asm("v_cvt_pk_bf16_f32 %0, %1, %2" : "=v"(w2) : "v"(p[4]), "v"(p[5]));
        asm("v_cvt_pk_bf16_f32 %0, %1, %2" : "=v"(w3) : "v"(p[6]), "v"(p[7]));
        asm("v_cvt_pk_bf16_f32 %0, %1, %2" : "=v"(y0) : "v"(p[8]), "v"(p[9]));
        asm("v_cvt_pk_bf16_f32 %0, %1, %2" : "=v"(y1) : "v"(p[10]), "v"(p[11]));
        asm("v_cvt_pk_bf16_f32 %0, %1, %2" : "=v"(y2) : "v"(p[12]), "v"(p[13]));
        asm("v_cvt_pk_bf16_f32 %0, %1, %2" : "=v"(y3) : "v"(p[14]), "v"(p[15]));
        asm volatile("v_permlane32_swap_b32 %0, %1" : "+v"(w0), "+v"(w2));
        asm volatile("v_permlane32_swap_b32 %0, %1" : "+v"(w1), "+v"(w3));
        asm volatile("v_permlane32_swap_b32 %0, %1" : "+v"(y0), "+v"(y2));
        asm volatile("v_permlane32_swap_b32 %0, %1" : "+v"(y1), "+v"(y3));
        int4 t1; t1.x = (int)w0; t1.y = (int)w1; t1.z = (int)w2; t1.w = (int)w3;
        int4 t2; t2.x = (int)y0; t2.y = (int)y1; t2.z = (int)y2; t2.w = (int)y3;
        s8v A1 = *(s8v*)&t1;
        s8v A2 = *(s8v*)&t2;

        // ---- PV: O += P . V   (V frags direct from global, fragment-major) ----
        const char* vp = vtb + (size_t)kblk * 4096 + laneoff;
        s8v b00 = *(const s8v*)(vp);             // k 0..15,  d 0..31
        s8v b01 = *(const s8v*)(vp + 1024);      // k 0..15,  d 32..63
        s8v b10 = *(const s8v*)(vp + 2048);      // k 16..31, d 0..31
        s8v b11 = *(const s8v*)(vp + 3072);      // k 16..31, d 32..63
        __builtin_amdgcn_s_setprio(1);
        o0 = MFMA32x32(A1, b00, o0);
        o0 = MFMA32x32(A2, b10, o0);
        o1 = MFMA32x32(A1, b01, o1);
        o1 = MFMA32x32(A2, b11, o1);
        __builtin_amdgcn_s_setprio(0);
    }

    // ---- merge 4 parity partials (tree: {2,3}->{0,1}, then 1->0) ----
    float* slotO0 = (float*)sm;                 // 32q x 64d
    float* slotO1 = (float*)(sm + 8192);
    float* slotM0 = (float*)(sm + 16384);       // m[32], l[32]
    float* slotM1 = (float*)(sm + 16896);

    __syncthreads();
    if (par >= 2) {
        float* so = (par == 2) ? slotO0 : slotO1;
        float* sM = (par == 2) ? slotM0 : slotM1;
        #pragma unroll
        for (int r = 0; r < 16; r++) {
            int qr = (r & 3) + 8 * (r >> 2) + h4;
            so[qr * 64 + l31] = o0[r];
            so[qr * 64 + 32 + l31] = o1[r];
        }
        if (lane < 32) { sM[lane] = m_run; sM[32 + lane] = l_run; }
    }
    __syncthreads();
    if (par < 2) {
        float* so = (par == 0) ? slotO0 : slotO1;
        float* sM = (par == 0) ? slotM0 : slotM1;
        float m2 = sM[l31], l2 = sM[32 + l31];
        float M = fmaxf(m_run, m2);
        float s1 = exp2f(m_run - M), s2 = exp2f(m2 - M);
        l_run = l_run * s1 + l2 * s2;
        m_run = M;
        #pragma unroll
        for (int r = 0; r < 16; r++) {
            int qr = (r & 3) + 8 * (r >> 2) + h4;
            float a = __shfl(s1, qr, 64), b = __shfl(s2, qr, 64);
            o0[r] = o0[r] * a + so[qr * 64 + l31] * b;
            o1[r] = o1[r] * a + so[qr * 64 + 32 + l31] * b;
        }
    }
    __syncthreads();
    if (par == 1) {
        #pragma unroll
        for (int r = 0; r < 16; r++) {
            int qr = (r & 3) + 8 * (r >> 2) + h4;
            slotO0[qr * 64 + l31] = o0[r];
            slotO0[qr * 64 + 32 + l31] = o1[r];
        }
        if (lane < 32) { slotM0[lane] = m_run; slotM0[32 + lane] = l_run; }
    }
    __syncthreads();
    if (par == 0) {
        float m2 = slotM0[l31], l2 = slotM0[32 + l31];
        float M = fmaxf(m_run, m2);
        float s1 = exp2f(m_run - M), s2 = exp2f(m2 - M);
        float lt = l_run * s1 + l2 * s2;
        float inv = 1.f / lt;
        float a0 = s1 * inv, b0 = s2 * inv;
        #pragma unroll
        for (int r = 0; r < 16; r++) {
            int qr = (r & 3) + 8 * (r >> 2) + h4;
            float a = __shfl(a0, qr, 64), b = __shfl(b0, qr, 64);
            float r0 = o0[r] * a + slotO0[qr * 64 + l31] * b;
            float r1 = o1[r] * a + slotO0[qr * 64 + 32 + l31] * b;
            size_t row = (size_t)bz * Nd + q0 + qr;
            aout[row * Dd + hh * 64 + l31] = __float2bfloat16(r0);
            aout[row * Dd + hh * 64 + 32 + l31] = __float2bfloat16(r1);
        }
    }
}

extern "C" void kernel_launch(void* const* d_in, const int* in_sizes, int n_in,
                              void* d_out, int out_size, void* d_ws, size_t ws_size,
                              hipStream_t stream) {
    const float* x    = (const float*)d_in[0];
    const int*   mask = (const int*)d_in[1];
    const float* WE   = (const float*)d_in[2];
    const float* bE   = (const float*)d_in[3];
    const float* WS   = (const float*)d_in[4];
    const float* bS   = (const float*)d_in[5];
    const float* WH   = (const float*)d_in[6];
    const float* bH   = (const float*)d_in[7];
    const float* Wrff = (const float*)d_in[8];
    const float* brff = (const float*)d_in[9];
    const float* alpha = (const float*)d_in[10];
    const float* beta  = (const float*)d_in[11];
    const float* gamma_ = (const float*)d_in[12];
    const float* delta = (const float*)d_in[13];
    const float* temperature = (const float*)d_in[14];
    const float* Wv = (const float*)d_in[15];
    const float* bv = (const float*)d_in[16];
    const float* Wo = (const float*)d_in[17];
    const float* bo = (const float*)d_in[18];

    char* ws = (char*)d_ws;
    unsigned short* wit = (unsigned short*)ws;             // 32768*320*2 = 20971520
    float* sq  = (float*)(ws + 20971520);                  // 32768*4*4   = 524288
    unsigned short* xb  = (unsigned short*)(ws + 21495808);// 2M*2        = 4194304
    unsigned short* wvb = (unsigned short*)(ws + 25690112);// 1M*2        = 2097152
    unsigned short* wob = (unsigned short*)(ws + 27787264);// 1M*2        = 2097152
    unsigned short* vt  = (unsigned short*)(ws + 29884416);// 2M*2        = 4194304
    __hip_bfloat16* aout = (__hip_bfloat16*)(ws + 34078720); // 2M*2      = 4194304

    witness_kernel<<<dim3(Bd * Hh * (Nd / NPB)), 64, 0, stream>>>(
        x, WE, bE, WS, bS, WH, bH, Wrff, brff, wit, sq, xb);

    cvt_kernel<<<dim3(1024), 256, 0, stream>>>(Wv, wvb, 1 << 20);
    cvt_kernel<<<dim3(1024), 256, 0, stream>>>(Wo, wob, 1 << 20);

    gemm_bf16_kernel<1><<<dim3(16, 32), 256, 0, stream>>>(xb, wvb, bv, nullptr, vt);

    attn_kernel<<<dim3(1024), 256, 0, stream>>>(
        wit, sq, vt, mask, alpha, beta, gamma_, delta, temperature, aout);

    gemm_bf16_kernel<0><<<dim3(16, 32), 256, 0, stream>>>(
        (const unsigned short*)aout, wob, bo, (float*)d_out, nullptr);
}

// Round 7
// 157.622 us; speedup vs baseline: 1.1608x; 1.0190x over previous
//
#include <hip/hip_runtime.h>
#include <hip/hip_bf16.h>
#include <math.h>
#include <stdint.h>

#define Bd 2
#define Nd 1024
#define Dd 1024
#define Hh 16
#define EPSf 1e-6f
#define NPB 8

typedef short s8v __attribute__((ext_vector_type(8)));
typedef float f16v __attribute__((ext_vector_type(16)));
typedef float f4v __attribute__((ext_vector_type(4)));

#define MFMA32x32(A,B,C) __builtin_amdgcn_mfma_f32_32x32x16_bf16(A,B,C,0,0,0)

__device__ __forceinline__ void gl_lds16(const void* g, void* l) {
    __builtin_amdgcn_global_load_lds((const __attribute__((address_space(1))) unsigned int*)g,
                                     (__attribute__((address_space(3))) unsigned int*)l, 16, 0, 0);
}

__device__ __forceinline__ unsigned short bf16bits(float v) {
    __hip_bfloat16 h = __float2bfloat16(v);
    return *(unsigned short*)&h;
}
__device__ __forceinline__ float bf16rt(float v) {   // round-trip through bf16
    __hip_bfloat16 h = __float2bfloat16(v);
    return __bfloat162float(h);
}

// bank-conflict-free slot permutation: 8 consecutive lanes cover all 8 16B bank groups
__device__ __forceinline__ int posf(int l, int h) {
    return ((l & 3) << 1) | ((l >> 2) & 1) | (h << 3) | ((l >> 3) << 4);
}

// ---------------- Kernel 1: witness projections -> fragment-major bf16 witness rows ----------------
// global layout: wit[bh][kblk=n>>5][c=f>>4][posf(n&31,(f>>3)&1)*8 + (f&7)]  (ushort; 1KB/chunk, 20KB/kblk)
// sq[row] = {|wE|^2 (+2e9 if key masked), |wHb|^2, 1-clip, |z|^2}
__global__ void witness_kernel(const float* __restrict__ x,
    const int* __restrict__ mask,
    const float* __restrict__ WE, const float* __restrict__ bE,
    const float* __restrict__ WS, const float* __restrict__ bS,
    const float* __restrict__ WH, const float* __restrict__ bH,
    const float* __restrict__ Wrff, const float* __restrict__ brff,
    unsigned short* __restrict__ wit, float* __restrict__ sqo,
    unsigned short* __restrict__ xb)
{
    const int e = threadIdx.x;           // 0..63
    int idx = blockIdx.x;
    const int NC = Nd / NPB;             // 128
    int nc = idx % NC;
    int h = (idx / NC) % Hh;
    int b = idx / (NC * Hh);
    int n0 = nc * NPB;
    size_t bh = (size_t)b * Hh + h;

    __shared__ float xs[NPB][64];
    __shared__ unsigned short wb[NPB][320];
    #pragma unroll
    for (int r = 0; r < NPB; r++) {
        float xv = x[((size_t)b * Nd + n0 + r) * Dd + h * 64 + e];
        xs[r][e] = xv;
        xb[((size_t)b * Nd + n0 + r) * Dd + h * 64 + e] = bf16bits(xv);
    }
    __syncthreads();

    size_t rowbase = (bh * Nd + n0);

    // ---- Euclidean (f = e) ----
    {
        float acc[NPB];
        #pragma unroll
        for (int r = 0; r < NPB; r++) acc[r] = 0.f;
        const float* Wp = WE + (size_t)h * 64 * 64 + e;
        for (int d = 0; d < 64; d++) {
            float w = Wp[(size_t)d * 64];
            #pragma unroll
            for (int r = 0; r < NPB; r++) acc[r] = fmaf(xs[r][d], w, acc[r]);
        }
        float bb = bE[h * 64 + e];
        #pragma unroll
        for (int r = 0; r < NPB; r++) {
            float v = acc[r] + bb;
            float vf = bf16rt(v);
            wb[r][e] = bf16bits(v);
            float s = vf * vf;
            for (int o = 32; o > 0; o >>= 1) s += __shfl_xor(s, o, 64);
            if (e == 0)
                sqo[(rowbase + r) * 4 + 0] = s + ((mask[b * Nd + n0 + r] > 0) ? 0.f : 2e9f);
        }
    }
    // ---- Spherical (f = 64+e) ----
    {
        float acc[NPB];
        #pragma unroll
        for (int r = 0; r < NPB; r++) acc[r] = 0.f;
        const float* Wp = WS + (size_t)h * 64 * 64 + e;
        for (int d = 0; d < 64; d++) {
            float w = Wp[(size_t)d * 64];
            #pragma unroll
            for (int r = 0; r < NPB; r++) acc[r] = fmaf(xs[r][d], w, acc[r]);
        }
        float bb = bS[h * 64 + e];
        #pragma unroll
        for (int r = 0; r < NPB; r++) {
            float v = acc[r] + bb;
            float s = v * v;
            for (int o = 32; o > 0; o >>= 1) s += __shfl_xor(s, o, 64);
            float nrm = sqrtf(s);
            wb[r][64 + e] = bf16bits(v / (nrm + EPSf));
        }
    }
    // ---- Hyperbolic (f = 128+e) ----
    {
        float acc[NPB];
        #pragma unroll
        for (int r = 0; r < NPB; r++) acc[r] = 0.f;
        const float* Wp = WH + (size_t)h * 64 * 64 + e;
        for (int d = 0; d < 64; d++) {
            float w = Wp[(size_t)d * 64];
            #pragma unroll
            for (int r = 0; r < NPB; r++) acc[r] = fmaf(xs[r][d], w, acc[r]);
        }
        float bb = bH[h * 64 + e];
        #pragma unroll
        for (int r = 0; r < NPB; r++) {
            float u = acc[r] + bb;
            float s = u * u;
            for (int o = 32; o > 0; o >>= 1) s += __shfl_xor(s, o, 64);
            float un = sqrtf(s);
            float sc = tanhf(un) / (un + EPSf);
            float w = sc * u;
            float wf = bf16rt(w);
            wb[r][128 + e] = bf16bits(w);
            float s2 = wf * wf;
            for (int o = 32; o > 0; o >>= 1) s2 += __shfl_xor(s2, o, 64);
            if (e == 0) {
                sqo[(rowbase + r) * 4 + 1] = s2;
                sqo[(rowbase + r) * 4 + 2] = 1.f - fminf(fmaxf(s2, 0.f), 1.f - 1e-5f);
            }
        }
    }
    // ---- RFF (f = 192+col) ----
    {
        float sF[NPB];
        #pragma unroll
        for (int r = 0; r < NPB; r++) sF[r] = 0.f;
        #pragma unroll
        for (int half = 0; half < 2; half++) {
            int col = e + 64 * half;
            float acc[NPB];
            #pragma unroll
            for (int r = 0; r < NPB; r++) acc[r] = 0.f;
            const float* Wp = Wrff + (size_t)h * 64 * 128 + col;
            for (int d = 0; d < 64; d++) {
                float w = Wp[(size_t)d * 128];
                #pragma unroll
                for (int r = 0; r < NPB; r++) acc[r] = fmaf(xs[r][d], w, acc[r]);
            }
            float bb = brff[h * 128 + col];
            #pragma unroll
            for (int r = 0; r < NPB; r++) {
                float zv = 0.125f * cosf(acc[r] + bb);
                float zf = bf16rt(zv);
                wb[r][192 + col] = bf16bits(zv);
                sF[r] += zf * zf;
            }
        }
        #pragma unroll
        for (int r = 0; r < NPB; r++) {
            float s = sF[r];
            for (int o = 32; o > 0; o >>= 1) s += __shfl_xor(s, o, 64);
            if (e == 0) sqo[(rowbase + r) * 4 + 3] = s;
        }
    }

    __syncthreads();
    // ---- coalesced 16B writeout of the 8 rows (320 slots) ----
    char* wgb = (char*)wit + bh * 655360 + (size_t)(n0 >> 5) * 20480;
    #pragma unroll
    for (int s = 0; s < 5; s++) {
        int slotid = s * 64 + e;
        int c = slotid >> 4, rem = slotid & 15, rr = rem >> 1, hh8 = rem & 1;
        int4 d = *(const int4*)((const char*)wb + rr * 640 + c * 32 + hh8 * 16);
        int l = (n0 & 31) + rr;
        *(int4*)(wgb + c * 1024 + posf(l, hh8) * 16) = d;
    }
}

// ---------------- convert two f32 arrays -> adjacent bf16 (Wv then Wo) ----------------
__global__ void cvt2_kernel(const float* __restrict__ a, const float* __restrict__ b2,
                            unsigned short* __restrict__ dst)
{
    int i = (blockIdx.x * blockDim.x + threadIdx.x) * 4;
    const float* s = (i < (1 << 20)) ? (a + i) : (b2 + (i - (1 << 20)));
    float4 v = *(const float4*)s;
    ushort4 o;
    o.x = bf16bits(v.x); o.y = bf16bits(v.y); o.z = bf16bits(v.z); o.w = bf16bits(v.w);
    *(ushort4*)(dst + i) = o;
}

// ---------------- bf16 MFMA GEMM: C[M x 1024] = A[M x 1024] * W[1024 x 1024]^T + bias ----------------
// 64x64 tile, 256 threads (4 waves, each one 32x32), XOR-swizzled LDS, double-buffered.
// MODE 0: f32 row-major to outF.  MODE 1: bf16 fragment-major vt2 (coalesced via LDS buffer).
template<int MODE>
__global__ __launch_bounds__(256) void gemm_bf16_kernel(
    const unsigned short* __restrict__ A, const unsigned short* __restrict__ Bw,
    const float* __restrict__ bias, float* __restrict__ outF, unsigned short* __restrict__ outV)
{
    __shared__ __align__(16) char sm[32768];   // 2 x (At 8192 + Bt 8192)
    int tid = threadIdx.x, lane = tid & 63;
    int w = tid >> 6, wm = w >> 1, wn = w & 1;
    int h8 = lane >> 5, l31 = lane & 31;
    int i0 = blockIdx.y * 64, j0 = blockIdx.x * 64;
    const char* Ab = (const char*)A;
    const char* Bb = (const char*)Bw;

    f16v acc = {};

    auto stage = [&](int kt, int buf) {
        char* atb = sm + buf * 16384;
        char* btb = atb + 8192;
        #pragma unroll
        for (int j = 0; j < 2; j++) {
            int elem = j * 256 + tid;
            int row = elem >> 3, u = elem & 7;
            int so = (u * 16) ^ ((row & 7) << 4);
            gl_lds16(Ab + (size_t)(i0 + row) * 2048 + kt * 128 + so, atb + elem * 16);
            gl_lds16(Bb + (size_t)(j0 + row) * 2048 + kt * 128 + so, btb + elem * 16);
        }
    };

    stage(0, 0);
    __syncthreads();
    for (int kt = 0; kt < 16; kt++) {
        int buf = kt & 1;
        if (kt < 15) stage(kt + 1, buf ^ 1);
        const char* atb = sm + buf * 16384;
        const char* btb = atb + 8192;
        int swz = (l31 & 7) << 4;
        #pragma unroll
        for (int kk = 0; kk < 4; kk++) {
            s8v a = *(const s8v*)(atb + (wm * 32 + l31) * 128 + ((kk * 32 + h8 * 16) ^ swz));
            s8v bq = *(const s8v*)(btb + (wn * 32 + l31) * 128 + ((kk * 32 + h8 * 16) ^ swz));
            acc = MFMA32x32(a, bq, acc);
        }
        __syncthreads();
    }

    if (MODE == 0) {
        #pragma unroll
        for (int r = 0; r < 16; r++) {
            int rf = (r & 3) + 8 * (r >> 2) + 4 * h8;
            int grow = i0 + wm * 32 + rf;
            int gcol = j0 + wn * 32 + l31;
            outF[(size_t)grow * 1024 + gcol] = acc[r] + bias[gcol];
        }
    } else {
        unsigned short* vbuf = (unsigned short*)sm;  // [2][4][64][8] = 8KB
        int gcol = j0 + wn * 32 + l31;
        float bb = bias[gcol];
        #pragma unroll
        for (int r = 0; r < 16; r++) {
            int rf = (r & 3) + 8 * (r >> 2) + 4 * h8;   // token within 64-tile is wm*32+rf; kk = rf
            vbuf[wm * 2048 + ((rf >> 4) * 2 + wn) * 512 + posf(l31, (rf >> 3) & 1) * 8 + (rf & 7)]
                = bf16bits(acc[r] + bb);
        }
        __syncthreads();
        int bh2 = (i0 >> 10) * 16 + (j0 >> 6);
        int nloc = i0 & 1023;
        #pragma unroll
        for (int j = 0; j < 2; j++) {
            int sid = j * 256 + tid;
            int wm2 = sid >> 8, chunk = (sid >> 6) & 3, slot = sid & 63;
            int kblkg = ((nloc + wm2 * 32) >> 5);
            *(int4*)((char*)outV + (size_t)bh2 * 131072 + kblkg * 4096 + chunk * 1024 + slot * 16)
                = *(const int4*)((const char*)sm + sid * 16);
        }
    }
}

// ---------------- Kernel 3: MFMA distances + online softmax + MFMA PV ----------------
// 1024 blocks (XCD-swizzled), 4 waves = 4-way k-parity over one 32-q tile.
// 2-PASS gram; mask folded into sq.x (no mkAll); LDS 36864 -> true 4 blocks/CU.
// V fragments hoisted before softmax to hide L2 latency under the exp chain.
// LDS: [0:16384) sqAll (merge: O-slots 2x8K, m/l at 16384); [16384:36864) Q
__global__ __launch_bounds__(256, 4) void attn_kernel(
    const unsigned short* __restrict__ wit, const float* __restrict__ sqb,
    const unsigned short* __restrict__ vt,
    const float* __restrict__ al_, const float* __restrict__ be_,
    const float* __restrict__ ga_, const float* __restrict__ de_,
    const float* __restrict__ tp_,
    __hip_bfloat16* __restrict__ aout)
{
    __shared__ __align__(16) char sm[36864];
    int tid = threadIdx.x, lane = tid & 63;
    int par = tid >> 6;                       // 0..3: k-parity
    int h8 = lane >> 5, l31 = lane & 31, h4 = h8 * 4;

    int bid = blockIdx.x;
    int xcd = bid & 7, slot = bid >> 3;       // slot 0..127
    int bh = (xcd << 2) | (slot >> 5);        // 0..31
    int qt = slot & 31;
    int bz = bh >> 4, hh = bh & 15;
    int q0 = qt * 32;

    const char* witb = (const char*)wit + (size_t)bh * 655360;
    const char* vtb = (const char*)vt + (size_t)bh * 131072;

    float* sqAll = (float*)sm;                       // [1024][4] (k-side only)
    char* qlds = sm + 16384;                         // 20KB Q tile (fragment-major)

    // ---- one-time stage: sq (16KB), Q tile (20KB) ----
    #pragma unroll
    for (int j = 0; j < 4; j++) {
        int blk = par * 4 + j;
        gl_lds16((const char*)sqb + (size_t)bh * 16384 + blk * 1024 + lane * 16,
                 sm + blk * 1024);
    }
    #pragma unroll
    for (int j = 0; j < 5; j++) {
        int ch = par * 5 + j;
        gl_lds16(witb + (size_t)qt * 20480 + ch * 1024 + lane * 16,
                 qlds + ch * 1024);
    }

    int laneoff = posf(l31, h8) * 16;

    f4v sqq = *(const f4v*)(sqb + ((size_t)bh * Nd + q0 + l31) * 4);
    const float LOG2E = 1.4426950408889634f;
    const float LN2 = 0.6931471805599453f;
    float itmp2 = LOG2E / tp_[hh];
    float al2 = -al_[hh] * itmp2;
    float be2 = -be_[hh] * itmp2;
    float de2 = -de_[hh] * itmp2;
    float gl2 = -ga_[hh] * itmp2 * LN2;       // dH computed as log2 -> fold ln2
    float sqqxE = sqq.x + EPSf, sqqwE = sqq.w + EPSf;
    float sqqy = sqq.y, sqqz = sqq.z;

    float m_run = -INFINITY, l_run = 0.f;
    f16v o0 = {}, o1 = {};

    __syncthreads();   // staging complete

    for (int it = 0; it < 8; it++) {
        int kblk = it * 4 + par;
        int k0 = kblk * 32;
        const char* kp = witb + (size_t)kblk * 20480 + laneoff;
        float p[16];

        // ---- PASS 1: grams E,S -> partial logits ----
        {
            __builtin_amdgcn_s_setprio(1);
            f16v aE = {}, aS = {};
            #pragma unroll
            for (int c = 0; c < 8; c++) {
                s8v a = *(const s8v*)(kp + c * 1024);
                s8v q = *(const s8v*)(qlds + c * 1024 + laneoff);
                if (c < 4) aE = MFMA32x32(a, q, aE);
                else       aS = MFMA32x32(a, q, aS);
            }
            __builtin_amdgcn_s_setprio(0);
            #pragma unroll
            for (int r = 0; r < 16; r++) {
                int kr = (r & 3) + 8 * (r >> 2) + h4;
                float skx = sqAll[(size_t)(k0 + kr) * 4];
                float sE = fmaxf(fmaf(-2.f, aE[r], sqqxE + skx), EPSf);
                float dE = __builtin_amdgcn_sqrtf(sE);
                float cv = aS[r];
                float ax = fminf(fabsf(cv), 1.f - EPSf);
                float sq1 = __builtin_amdgcn_sqrtf(1.f - ax);
                float pa = sq1 * fmaf(ax, fmaf(ax, fmaf(ax, -0.0187293f, 0.0742610f), -0.2121144f), 1.5707288f);
                float dS = (cv < 0.f) ? (3.14159265f - pa) : pa;
                p[r] = fmaf(al2, dE, be2 * dS);
            }
        }

        // ---- PASS 2: grams H,F -> final logits ----
        {
            __builtin_amdgcn_s_setprio(1);
            f16v aH = {}, aF = {};
            #pragma unroll
            for (int c = 8; c < 20; c++) {
                s8v a = *(const s8v*)(kp + c * 1024);
                s8v q = *(const s8v*)(qlds + c * 1024 + laneoff);
                if (c < 12) aH = MFMA32x32(a, q, aH);
                else        aF = MFMA32x32(a, q, aF);
            }
            __builtin_amdgcn_s_setprio(0);
            #pragma unroll
            for (int r = 0; r < 16; r++) {
                int kr = (r & 3) + 8 * (r >> 2) + h4;
                const float4 sk = *(const float4*)(sqAll + (size_t)(k0 + kr) * 4);
                float d2 = fmaxf(fmaf(-2.f, aH[r], sqqy + sk.y), 0.f);
                float den = fmaf(sqqz, sk.z, EPSf);
                float arx = fmaxf(fmaf(d2 + d2, __builtin_amdgcn_rcpf(den), 1.f), 1.f + EPSf);
                float sh = __builtin_amdgcn_sqrtf(fmaf(arx, arx, -1.f));
                float lH = log2f(arx + sh);
                float sF = fmaxf(fmaf(-2.f, aF[r], sqqwE + sk.w), EPSf);
                float dF = __builtin_amdgcn_sqrtf(sF);
                p[r] = fmaf(de2, dF, fmaf(gl2, lH, p[r]));
            }
        }

        // ---- V fragment loads hoisted: latency hides under softmax/exp chain ----
        const char* vp = vtb + (size_t)kblk * 4096 + laneoff;
        s8v b00 = *(const s8v*)(vp);             // k 0..15,  d 0..31
        s8v b01 = *(const s8v*)(vp + 1024);      // k 0..15,  d 32..63
        s8v b10 = *(const s8v*)(vp + 2048);      // k 16..31, d 0..31
        s8v b11 = *(const s8v*)(vp + 3072);      // k 16..31, d 32..63

        // ---- online softmax with defer-max (THR = 8 in log2 units) ----
        float mt = p[0];
        #pragma unroll
        for (int r = 1; r < 16; r++) mt = fmaxf(mt, p[r]);
        mt = fmaxf(mt, __shfl_xor(mt, 32, 64));
        if (!__all(mt <= m_run + 8.f)) {
            float mnew = fmaxf(m_run, mt);
            float sc = exp2f(m_run - mnew);
            l_run *= sc;
            m_run = mnew;
            #pragma unroll
            for (int r = 0; r < 16; r++) {
                float s = __shfl(sc, (r & 3) + 8 * (r >> 2) + h4, 64);
                o0[r] *= s; o1[r] *= s;
            }
        }
        float ps = 0.f;
        #pragma unroll
        for (int r = 0; r < 16; r++) { p[r] = exp2f(p[r] - m_run); ps += p[r]; }
        ps += __shfl_xor(ps, 32, 64);
        l_run += ps;

        // ---- P relayout: f32 (D-layout) -> bf16 A-frags via cvt_pk + permlane32_swap ----
        unsigned int w0, w1, w2, w3, y0, y1, y2, y3;
        asm("v_cvt_pk_bf16_f32 %0, %1, %2" : "=v"(w0) : "v"(p[0]), "v"(p[1]));
        asm("v_cvt_pk_bf16_f32 %0, %1, %2" : "=v"(w1) : "v"(p[2]), "v"(p[3]));
        asm("v_cvt_pk_bf16_f32 %0, %1, %2" : "=v"(w2) : "v"(p[4]), "v"(p[5]));
        asm("v_cvt_pk_bf16_f32 %0, %1, %2" : "=v"(w3) : "v"(p[6]), "v"(p[7]));
        asm("v_cvt_pk_bf16_f32 %0, %1, %2" : "=v"(y0) : "v"(p[8]), "v"(p[9]));
        asm("v_cvt_pk_bf16_f32 %0, %1, %2" : "=v"(y1) : "v"(p[10]), "v"(p[11]));
        asm("v_cvt_pk_bf16_f32 %0, %1, %2" : "=v"(y2) : "v"(p[12]), "v"(p[13]));
        asm("v_cvt_pk_bf16_f32 %0, %1, %2" : "=v"(y3) : "v"(p[14]), "v"(p[15]));
        asm volatile("v_permlane32_swap_b32 %0, %1" : "+v"(w0), "+v"(w2));
        asm volatile("v_permlane32_swap_b32 %0, %1" : "+v"(w1), "+v"(w3));
        asm volatile("v_permlane32_swap_b32 %0, %1" : "+v"(y0), "+v"(y2));
        asm volatile("v_permlane32_swap_b32 %0, %1" : "+v"(y1), "+v"(y3));
        int4 t1; t1.x = (int)w0; t1.y = (int)w1; t1.z = (int)w2; t1.w = (int)w3;
        int4 t2; t2.x = (int)y0; t2.y = (int)y1; t2.z = (int)y2; t2.w = (int)y3;
        s8v A1 = *(s8v*)&t1;
        s8v A2 = *(s8v*)&t2;

        // ---- PV: O += P . V ----
        __builtin_amdgcn_s_setprio(1);
        o0 = MFMA32x32(A1, b00, o0);
        o0 = MFMA32x32(A2, b10, o0);
        o1 = MFMA32x32(A1, b01, o1);
        o1 = MFMA32x32(A2, b11, o1);
        __builtin_amdgcn_s_setprio(0);
    }

    // ---- merge 4 parity partials (tree: {2,3}->{0,1}, then 1->0) ----
    float* slotO0 = (float*)sm;                 // 32q x 64d
    float* slotO1 = (float*)(sm + 8192);
    float* slotM0 = (float*)(sm + 16384);       // m[32], l[32]
    float* slotM1 = (float*)(sm + 16896);

    __syncthreads();
    if (par >= 2) {
        float* so = (par == 2) ? slotO0 : slotO1;
        float* sM = (par == 2) ? slotM0 : slotM1;
        #pragma unroll
        for (int r = 0; r < 16; r++) {
            int qr = (r & 3) + 8 * (r >> 2) + h4;
            so[qr * 64 + l31] = o0[r];
            so[qr * 64 + 32 + l31] = o1[r];
        }
        if (lane < 32) { sM[lane] = m_run; sM[32 + lane] = l_run; }
    }
    __syncthreads();
    if (par < 2) {
        float* so = (par == 0) ? slotO0 : slotO1;
        float* sM = (par == 0) ? slotM0 : slotM1;
        float m2 = sM[l31], l2 = sM[32 + l31];
        float M = fmaxf(m_run, m2);
        float s1 = exp2f(m_run - M), s2 = exp2f(m2 - M);
        l_run = l_run * s1 + l2 * s2;
        m_run = M;
        #pragma unroll
        for (int r = 0; r < 16; r++) {
            int qr = (r & 3) + 8 * (r >> 2) + h4;
            float a = __shfl(s1, qr, 64), b = __shfl(s2, qr, 64);
            o0[r] = o0[r] * a + so[qr * 64 + l31] * b;
            o1[r] = o1[r] * a + so[qr * 64 + 32 + l31] * b;
        }
    }
    __syncthreads();
    if (par == 1) {
        #pragma unroll
        for (int r = 0; r < 16; r++) {
            int qr = (r & 3) + 8 * (r >> 2) + h4;
            slotO0[qr * 64 + l31] = o0[r];
            slotO0[qr * 64 + 32 + l31] = o1[r];
        }
        if (lane < 32) { slotM0[lane] = m_run; slotM0[32 + lane] = l_run; }
    }
    __syncthreads();
    if (par == 0) {
        float m2 = slotM0[l31], l2 = slotM0[32 + l31];
        float M = fmaxf(m_run, m2);
        float s1 = exp2f(m_run - M), s2 = exp2f(m2 - M);
        float lt = l_run * s1 + l2 * s2;
        float inv = 1.f / lt;
        float a0 = s1 * inv, b0 = s2 * inv;
        #pragma unroll
        for (int r = 0; r < 16; r++) {
            int qr = (r & 3) + 8 * (r >> 2) + h4;
            float a = __shfl(a0, qr, 64), b = __shfl(b0, qr, 64);
            float r0 = o0[r] * a + slotO0[qr * 64 + l31] * b;
            float r1 = o1[r] * a + slotO0[qr * 64 + 32 + l31] * b;
            size_t row = (size_t)bz * Nd + q0 + qr;
            aout[row * Dd + hh * 64 + l31] = __float2bfloat16(r0);
            aout[row * Dd + hh * 64 + 32 + l31] = __float2bfloat16(r1);
        }
    }
}

extern "C" void kernel_launch(void* const* d_in, const int* in_sizes, int n_in,
                              void* d_out, int out_size, void* d_ws, size_t ws_size,
                              hipStream_t stream) {
    const float* x    = (const float*)d_in[0];
    const int*   mask = (const int*)d_in[1];
    const float* WE   = (const float*)d_in[2];
    const float* bE   = (const float*)d_in[3];
    const float* WS   = (const float*)d_in[4];
    const float* bS   = (const float*)d_in[5];
    const float* WH   = (const float*)d_in[6];
    const float* bH   = (const float*)d_in[7];
    const float* Wrff = (const float*)d_in[8];
    const float* brff = (const float*)d_in[9];
    const float* alpha = (const float*)d_in[10];
    const float* beta  = (const float*)d_in[11];
    const float* gamma_ = (const float*)d_in[12];
    const float* delta = (const float*)d_in[13];
    const float* temperature = (const float*)d_in[14];
    const float* Wv = (const float*)d_in[15];
    const float* bv = (const float*)d_in[16];
    const float* Wo = (const float*)d_in[17];
    const float* bo = (const float*)d_in[18];

    char* ws = (char*)d_ws;
    unsigned short* wit = (unsigned short*)ws;             // 32768*320*2 = 20971520
    float* sq  = (float*)(ws + 20971520);                  // 32768*4*4   = 524288
    unsigned short* xb  = (unsigned short*)(ws + 21495808);// 2M*2        = 4194304
    unsigned short* wvb = (unsigned short*)(ws + 25690112);// 1M*2        = 2097152
    unsigned short* wob = (unsigned short*)(ws + 27787264);// 1M*2        = 2097152 (contiguous after wvb)
    unsigned short* vt  = (unsigned short*)(ws + 29884416);// 2M*2        = 4194304
    __hip_bfloat16* aout = (__hip_bfloat16*)(ws + 34078720); // 2M*2      = 4194304

    witness_kernel<<<dim3(Bd * Hh * (Nd / NPB)), 64, 0, stream>>>(
        x, mask, WE, bE, WS, bS, WH, bH, Wrff, brff, wit, sq, xb);

    cvt2_kernel<<<dim3(2048), 256, 0, stream>>>(Wv, Wo, wvb);

    gemm_bf16_kernel<1><<<dim3(16, 32), 256, 0, stream>>>(xb, wvb, bv, nullptr, vt);

    attn_kernel<<<dim3(1024), 256, 0, stream>>>(
        wit, sq, vt, alpha, beta, gamma_, delta, temperature, aout);

    gemm_bf16_kernel<0><<<dim3(16, 32), 256, 0, stream>>>(
        (const unsigned short*)aout, wob, bo, (float*)d_out, nullptr);
}

// Round 8
// 129.641 us; speedup vs baseline: 1.4113x; 1.2158x over previous
//
#include <hip/hip_runtime.h>
#include <hip/hip_bf16.h>
#include <math.h>
#include <stdint.h>

#define Bd 2
#define Nd 1024
#define Dd 1024
#define Hh 16
#define EPSf 1e-6f

typedef short s8v __attribute__((ext_vector_type(8)));
typedef float f16v __attribute__((ext_vector_type(16)));
typedef float f4v __attribute__((ext_vector_type(4)));

#define MFMA32x32(A,B,C) __builtin_amdgcn_mfma_f32_32x32x16_bf16(A,B,C,0,0,0)
#define PKB(d,a,b) asm("v_cvt_pk_bf16_f32 %0, %1, %2" : "=v"(d) : "v"(a), "v"(b))
#define SWL(a,b) asm volatile("v_permlane32_swap_b32 %0, %1" : "+v"(a), "+v"(b))
#define RMAP(r) (((r) & 3) + 8 * ((r) >> 2))

__device__ __forceinline__ void gl_lds16(const void* g, void* l) {
    __builtin_amdgcn_global_load_lds((const __attribute__((address_space(1))) unsigned int*)g,
                                     (__attribute__((address_space(3))) unsigned int*)l, 16, 0, 0);
}

__device__ __forceinline__ unsigned short bf16bits(float v) {
    __hip_bfloat16 h = __float2bfloat16(v);
    return *(unsigned short*)&h;
}

// bank-conflict-free slot permutation: 8 consecutive lanes cover all 8 16B bank groups
__device__ __forceinline__ int posf(int l, int h) {
    return ((l & 3) << 1) | ((l >> 2) & 1) | (h << 3) | ((l >> 3) << 4);
}

// ---------------- Kernel 0: prep ----------------
// bid < 2048: convert Wv|Wo f32 -> bf16 (contiguous 2M elements).
// bid >= 2048: pack witness weights into MFMA A-operand fragment layout, hi+lo bf16 split.
// wfH/wfL layout: [h][fg(10)][c(4)] chunks of 1KB; slot posf(l31,h8)*16B holds
//   A[row=f=fg*32+l31][k=d=c*16+h8*8+j] j=0..7.
__global__ __launch_bounds__(256) void prep_kernel(
    const float* __restrict__ Wv, const float* __restrict__ Wo, unsigned short* __restrict__ wcvt,
    const float* __restrict__ WE, const float* __restrict__ WS,
    const float* __restrict__ WH, const float* __restrict__ Wrff,
    unsigned short* __restrict__ wfH, unsigned short* __restrict__ wfL)
{
    int bid = blockIdx.x, tid = threadIdx.x;
    if (bid < 2048) {
        int i = (bid * 256 + tid) * 4;
        const float* s = (i < (1 << 20)) ? (Wv + i) : (Wo + (i - (1 << 20)));
        float4 v = *(const float4*)s;
        ushort4 o;
        o.x = bf16bits(v.x); o.y = bf16bits(v.y); o.z = bf16bits(v.z); o.w = bf16bits(v.w);
        *(ushort4*)(wcvt + i) = o;
    } else {
        int g = (bid - 2048) * 4 + (tid >> 6);        // 0..639
        int lane = tid & 63, l31 = lane & 31, h8 = lane >> 5;
        int h = g / 40, rem = g % 40, fg = rem >> 2, c = rem & 3;
        int f = fg * 32 + l31;
        unsigned int hw[4] = {0, 0, 0, 0}, lw[4] = {0, 0, 0, 0};
        #pragma unroll
        for (int j = 0; j < 8; j++) {
            int d = c * 16 + h8 * 8 + j;
            float wv_;
            if (f < 64)       wv_ = WE[(h * 64 + d) * 64 + f];
            else if (f < 128) wv_ = WS[(h * 64 + d) * 64 + (f - 64)];
            else if (f < 192) wv_ = WH[(h * 64 + d) * 64 + (f - 128)];
            else              wv_ = Wrff[(h * 64 + d) * 128 + (f - 192)];
            unsigned int hb = bf16bits(wv_);
            unsigned int hfb = hb << 16;
            float hf = *(float*)&hfb;
            unsigned int lb = bf16bits(wv_ - hf);
            hw[j >> 1] |= hb << ((j & 1) * 16);
            lw[j >> 1] |= lb << ((j & 1) * 16);
        }
        int off = g * 512 + posf(l31, h8) * 8;        // ushort units
        int4 th; th.x = (int)hw[0]; th.y = (int)hw[1]; th.z = (int)hw[2]; th.w = (int)hw[3];
        int4 tl; tl.x = (int)lw[0]; tl.y = (int)lw[1]; tl.z = (int)lw[2]; tl.w = (int)lw[3];
        *(int4*)(wfH + off) = th;
        *(int4*)(wfL + off) = tl;
    }
}

// ---------------- Kernel 1: MFMA witness projections ----------------
// grid (8 ntiles, 16 h, 2 b) x 256 threads; each wave owns 32 tokens.
// Projects x[128x64] onto 320 features via 3-term bf16-split MFMA, applies the
// per-witness nonlinearities in-register, and emits the fragment-major wit layout
// (identical to rounds 5-7) plus sq and xb.
__global__ __launch_bounds__(256) void witness_kernel(
    const float* __restrict__ x, const int* __restrict__ mask,
    const float* __restrict__ bE, const float* __restrict__ bS,
    const float* __restrict__ bH, const float* __restrict__ brff,
    const unsigned short* __restrict__ wfH, const unsigned short* __restrict__ wfL,
    unsigned short* __restrict__ wit, float* __restrict__ sqo,
    unsigned short* __restrict__ xb)
{
    __shared__ __align__(16) float xw[128 * 68 + 320];
    float* biasL = xw + 128 * 68;

    int tid = threadIdx.x, lane = tid & 63, w = tid >> 6;
    int l31 = lane & 31, h8 = lane >> 5;
    int nt = blockIdx.x, h = blockIdx.y, b = blockIdx.z;
    int n0 = nt * 128;
    size_t bh = (size_t)b * Hh + h;

    // ---- coalesced x-tile load -> LDS (f32) + xb (bf16 global) ----
    #pragma unroll
    for (int i = 0; i < 32; i++) {
        int idx = i * 256 + tid;
        int row = idx >> 6, col = idx & 63;
        float xv = x[((size_t)(b * Nd + n0 + row)) * Dd + h * 64 + col];
        xw[row * 68 + col] = xv;
        xb[((size_t)(b * Nd + n0 + row)) * Dd + h * 64 + col] = bf16bits(xv);
    }
    if (tid < 320) {
        int f = tid;
        float bv_;
        if (f < 64)       bv_ = bE[h * 64 + f];
        else if (f < 128) bv_ = bS[h * 64 + f - 64];
        else if (f < 192) bv_ = bH[h * 64 + f - 128];
        else              bv_ = brff[h * 128 + f - 192];
        biasL[f] = bv_;
    }
    __syncthreads();

    // ---- build x B-frags (hi + lo split) ----
    int tok = w * 32 + l31;
    s8v bxh[4], bxl[4];
    #pragma unroll
    for (int c = 0; c < 4; c++) {
        const float* xp = &xw[tok * 68 + c * 16 + h8 * 8];
        float4 u0 = *(const float4*)xp;
        float4 u1 = *(const float4*)(xp + 4);
        float e[8] = {u0.x, u0.y, u0.z, u0.w, u1.x, u1.y, u1.z, u1.w};
        unsigned int hwv[4], lwv[4];
        #pragma unroll
        for (int k = 0; k < 4; k++) {
            unsigned int hb0 = bf16bits(e[2 * k]), hb1 = bf16bits(e[2 * k + 1]);
            unsigned int f0b = hb0 << 16, f1b = hb1 << 16;
            float f0 = *(float*)&f0b, f1 = *(float*)&f1b;
            unsigned int lb0 = bf16bits(e[2 * k] - f0), lb1 = bf16bits(e[2 * k + 1] - f1);
            hwv[k] = hb0 | (hb1 << 16);
            lwv[k] = lb0 | (lb1 << 16);
        }
        int4 th; th.x = (int)hwv[0]; th.y = (int)hwv[1]; th.z = (int)hwv[2]; th.w = (int)hwv[3];
        int4 tl; tl.x = (int)lwv[0]; tl.y = (int)lwv[1]; tl.z = (int)lwv[2]; tl.w = (int)lwv[3];
        bxh[c] = *(s8v*)&th;
        bxl[c] = *(s8v*)&tl;
    }

    const char* wfh = (const char*)wfH + (size_t)h * 40960;
    const char* wfl = (const char*)wfL + (size_t)h * 40960;
    int loff = posf(l31, h8) * 16;
    char* witg = (char*)wit + bh * 655360 + (size_t)(nt * 4 + w) * 20480;
    int R0 = 4 * h8;

    auto proj = [&](int fg) -> f16v {
        f16v acc = {};
        #pragma unroll
        for (int c = 0; c < 4; c++) {
            s8v aH_ = *(const s8v*)(wfh + ((fg * 4 + c) << 10) + loff);
            s8v aL_ = *(const s8v*)(wfl + ((fg * 4 + c) << 10) + loff);
            acc = MFMA32x32(aH_, bxh[c], acc);
            acc = MFMA32x32(aL_, bxh[c], acc);
            acc = MFMA32x32(aH_, bxl[c], acc);
        }
        return acc;
    };

    // emit: round 16 f32 -> bf16 frags, optionally accumulate sum of rounded squares,
    // permlane-swap to contiguous-feature quads, store chunks cc0, cc0+1.
    auto emit = [&](const float* vv, int cc0, float* sqp) {
        unsigned int p0, p1, p2, p3, p4, p5, p6, p7;
        PKB(p0, vv[0], vv[1]);   PKB(p1, vv[2], vv[3]);
        PKB(p2, vv[4], vv[5]);   PKB(p3, vv[6], vv[7]);
        PKB(p4, vv[8], vv[9]);   PKB(p5, vv[10], vv[11]);
        PKB(p6, vv[12], vv[13]); PKB(p7, vv[14], vv[15]);
        if (sqp) {
            float s = *sqp;
            unsigned int ws_[8] = {p0, p1, p2, p3, p4, p5, p6, p7};
            #pragma unroll
            for (int k = 0; k < 8; k++) {
                unsigned int lobits = ws_[k] << 16, hibits = ws_[k] & 0xffff0000u;
                float lo = *(float*)&lobits, hi = *(float*)&hibits;
                s = fmaf(lo, lo, fmaf(hi, hi, s));
            }
            *sqp = s;
        }
        SWL(p0, p2); SWL(p1, p3); SWL(p4, p6); SWL(p5, p7);
        int4 t1; t1.x = (int)p0; t1.y = (int)p1; t1.z = (int)p2; t1.w = (int)p3;
        int4 t2; t2.x = (int)p4; t2.y = (int)p5; t2.z = (int)p6; t2.w = (int)p7;
        *(int4*)(witg + cc0 * 1024 + loff) = t1;
        *(int4*)(witg + cc0 * 1024 + 1024 + loff) = t2;
    };

    float vv[16];

    // ---- Euclidean: fg 0,1 -> chunks 0-3, sqE from rounded ----
    float sE_ = 0.f;
    {
        f16v a0 = proj(0);
        #pragma unroll
        for (int r = 0; r < 16; r++) vv[r] = a0[r] + biasL[0 + RMAP(r) + R0];
        emit(vv, 0, &sE_);
        f16v a1 = proj(1);
        #pragma unroll
        for (int r = 0; r < 16; r++) vv[r] = a1[r] + biasL[32 + RMAP(r) + R0];
        emit(vv, 2, &sE_);
    }
    sE_ += __shfl_xor(sE_, 32, 64);

    // ---- Spherical: fg 2,3 -> chunks 4-7 (normalize pre-rounding) ----
    {
        f16v a2 = proj(2), a3 = proj(3);
        float v2[16], v3[16], ns = 0.f;
        #pragma unroll
        for (int r = 0; r < 16; r++) {
            v2[r] = a2[r] + biasL[64 + RMAP(r) + R0];
            v3[r] = a3[r] + biasL[96 + RMAP(r) + R0];
            ns = fmaf(v2[r], v2[r], fmaf(v3[r], v3[r], ns));
        }
        ns += __shfl_xor(ns, 32, 64);
        float inv = __builtin_amdgcn_rcpf(sqrtf(ns) + EPSf);
        #pragma unroll
        for (int r = 0; r < 16; r++) { v2[r] *= inv; v3[r] *= inv; }
        emit(v2, 4, nullptr);
        emit(v3, 6, nullptr);
    }

    // ---- Hyperbolic: fg 4,5 -> chunks 8-11, sq from rounded ----
    float s2_ = 0.f, sq2v;
    {
        f16v a4 = proj(4), a5 = proj(5);
        float u4[16], u5[16], us = 0.f;
        #pragma unroll
        for (int r = 0; r < 16; r++) {
            u4[r] = a4[r] + biasL[128 + RMAP(r) + R0];
            u5[r] = a5[r] + biasL[160 + RMAP(r) + R0];
            us = fmaf(u4[r], u4[r], fmaf(u5[r], u5[r], us));
        }
        us += __shfl_xor(us, 32, 64);
        float un = sqrtf(us);
        float sc = tanhf(un) * __builtin_amdgcn_rcpf(un + EPSf);
        #pragma unroll
        for (int r = 0; r < 16; r++) { u4[r] *= sc; u5[r] *= sc; }
        emit(u4, 8, &s2_);
        emit(u5, 10, &s2_);
    }
    s2_ += __shfl_xor(s2_, 32, 64);
    sq2v = 1.f - fminf(fmaxf(s2_, 0.f), 1.f - 1e-5f);

    // ---- RFF: fg 6..9 -> chunks 12-19, sq from rounded ----
    float zq = 0.f;
    #pragma unroll
    for (int fg = 6; fg < 10; fg++) {
        f16v af = proj(fg);
        #pragma unroll
        for (int r = 0; r < 16; r++)
            vv[r] = 0.125f * __cosf(af[r] + biasL[fg * 32 + RMAP(r) + R0]);
        emit(vv, (fg - 6) * 2 + 12, &zq);
    }
    zq += __shfl_xor(zq, 32, 64);

    // ---- sq writeout (h8==0 lanes; mask folded into sq.x) ----
    if (h8 == 0) {
        int m = mask[b * Nd + n0 + tok];
        f4v s4;
        s4.x = sE_ + ((m > 0) ? 0.f : 2e9f);
        s4.y = s2_;
        s4.z = sq2v;
        s4.w = zq;
        *(f4v*)(sqo + ((bh << 10) + n0 + tok) * 4) = s4;
    }
}

// ---------------- bf16 MFMA GEMM: C[M x 1024] = A[M x 1024] * W[1024 x 1024]^T + bias ----------------
// 64x64 tile, 256 threads (4 waves, each one 32x32), XOR-swizzled LDS, double-buffered.
// MODE 0: f32 row-major to outF.  MODE 1: bf16 fragment-major vt2 (coalesced via LDS buffer).
template<int MODE>
__global__ __launch_bounds__(256) void gemm_bf16_kernel(
    const unsigned short* __restrict__ A, const unsigned short* __restrict__ Bw,
    const float* __restrict__ bias, float* __restrict__ outF, unsigned short* __restrict__ outV)
{
    __shared__ __align__(16) char sm[32768];   // 2 x (At 8192 + Bt 8192)
    int tid = threadIdx.x, lane = tid & 63;
    int w = tid >> 6, wm = w >> 1, wn = w & 1;
    int h8 = lane >> 5, l31 = lane & 31;
    int i0 = blockIdx.y * 64, j0 = blockIdx.x * 64;
    const char* Ab = (const char*)A;
    const char* Bb = (const char*)Bw;

    f16v acc = {};

    auto stage = [&](int kt, int buf) {
        char* atb = sm + buf * 16384;
        char* btb = atb + 8192;
        #pragma unroll
        for (int j = 0; j < 2; j++) {
            int elem = j * 256 + tid;
            int row = elem >> 3, u = elem & 7;
            int so = (u * 16) ^ ((row & 7) << 4);
            gl_lds16(Ab + (size_t)(i0 + row) * 2048 + kt * 128 + so, atb + elem * 16);
            gl_lds16(Bb + (size_t)(j0 + row) * 2048 + kt * 128 + so, btb + elem * 16);
        }
    };

    stage(0, 0);
    __syncthreads();
    for (int kt = 0; kt < 16; kt++) {
        int buf = kt & 1;
        if (kt < 15) stage(kt + 1, buf ^ 1);
        const char* atb = sm + buf * 16384;
        const char* btb = atb + 8192;
        int swz = (l31 & 7) << 4;
        #pragma unroll
        for (int kk = 0; kk < 4; kk++) {
            s8v a = *(const s8v*)(atb + (wm * 32 + l31) * 128 + ((kk * 32 + h8 * 16) ^ swz));
            s8v bq = *(const s8v*)(btb + (wn * 32 + l31) * 128 + ((kk * 32 + h8 * 16) ^ swz));
            acc = MFMA32x32(a, bq, acc);
        }
        __syncthreads();
    }

    if (MODE == 0) {
        #pragma unroll
        for (int r = 0; r < 16; r++) {
            int rf = (r & 3) + 8 * (r >> 2) + 4 * h8;
            int grow = i0 + wm * 32 + rf;
            int gcol = j0 + wn * 32 + l31;
            outF[(size_t)grow * 1024 + gcol] = acc[r] + bias[gcol];
        }
    } else {
        unsigned short* vbuf = (unsigned short*)sm;  // [2][4][64][8] = 8KB
        int gcol = j0 + wn * 32 + l31;
        float bb = bias[gcol];
        #pragma unroll
        for (int r = 0; r < 16; r++) {
            int rf = (r & 3) + 8 * (r >> 2) + 4 * h8;
            vbuf[wm * 2048 + ((rf >> 4) * 2 + wn) * 512 + posf(l31, (rf >> 3) & 1) * 8 + (rf & 7)]
                = bf16bits(acc[r] + bb);
        }
        __syncthreads();
        int bh2 = (i0 >> 10) * 16 + (j0 >> 6);
        int nloc = i0 & 1023;
        #pragma unroll
        for (int j = 0; j < 2; j++) {
            int sid = j * 256 + tid;
            int wm2 = sid >> 8, chunk = (sid >> 6) & 3, slot = sid & 63;
            int kblkg = ((nloc + wm2 * 32) >> 5);
            *(int4*)((char*)outV + (size_t)bh2 * 131072 + kblkg * 4096 + chunk * 1024 + slot * 16)
                = *(const int4*)((const char*)sm + sid * 16);
        }
    }
}

// ---------------- Kernel 3: MFMA distances + online softmax + MFMA PV ----------------
// (unchanged from round 7)
__global__ __launch_bounds__(256, 4) void attn_kernel(
    const unsigned short* __restrict__ wit, const float* __restrict__ sqb,
    const unsigned short* __restrict__ vt,
    const float* __restrict__ al_, const float* __restrict__ be_,
    const float* __restrict__ ga_, const float* __restrict__ de_,
    const float* __restrict__ tp_,
    __hip_bfloat16* __restrict__ aout)
{
    __shared__ __align__(16) char sm[36864];
    int tid = threadIdx.x, lane = tid & 63;
    int par = tid >> 6;
    int h8 = lane >> 5, l31 = lane & 31, h4 = h8 * 4;

    int bid = blockIdx.x;
    int xcd = bid & 7, slot = bid >> 3;
    int bh = (xcd << 2) | (slot >> 5);
    int qt = slot & 31;
    int bz = bh >> 4, hh = bh & 15;
    int q0 = qt * 32;

    const char* witb = (const char*)wit + (size_t)bh * 655360;
    const char* vtb = (const char*)vt + (size_t)bh * 131072;

    float* sqAll = (float*)sm;
    char* qlds = sm + 16384;

    #pragma unroll
    for (int j = 0; j < 4; j++) {
        int blk = par * 4 + j;
        gl_lds16((const char*)sqb + (size_t)bh * 16384 + blk * 1024 + lane * 16,
                 sm + blk * 1024);
    }
    #pragma unroll
    for (int j = 0; j < 5; j++) {
        int ch = par * 5 + j;
        gl_lds16(witb + (size_t)qt * 20480 + ch * 1024 + lane * 16,
                 qlds + ch * 1024);
    }

    int laneoff = posf(l31, h8) * 16;

    f4v sqq = *(const f4v*)(sqb + ((size_t)bh * Nd + q0 + l31) * 4);
    const float LOG2E = 1.4426950408889634f;
    const float LN2 = 0.6931471805599453f;
    float itmp2 = LOG2E / tp_[hh];
    float al2 = -al_[hh] * itmp2;
    float be2 = -be_[hh] * itmp2;
    float de2 = -de_[hh] * itmp2;
    float gl2 = -ga_[hh] * itmp2 * LN2;
    float sqqxE = sqq.x + EPSf, sqqwE = sqq.w + EPSf;
    float sqqy = sqq.y, sqqz = sqq.z;

    float m_run = -INFINITY, l_run = 0.f;
    f16v o0 = {}, o1 = {};

    __syncthreads();

    for (int it = 0; it < 8; it++) {
        int kblk = it * 4 + par;
        int k0 = kblk * 32;
        const char* kp = witb + (size_t)kblk * 20480 + laneoff;
        float p[16];

        {
            __builtin_amdgcn_s_setprio(1);
            f16v aE = {}, aS = {};
            #pragma unroll
            for (int c = 0; c < 8; c++) {
                s8v a = *(const s8v*)(kp + c * 1024);
                s8v q = *(const s8v*)(qlds + c * 1024 + laneoff);
                if (c < 4) aE = MFMA32x32(a, q, aE);
                else       aS = MFMA32x32(a, q, aS);
            }
            __builtin_amdgcn_s_setprio(0);
            #pragma unroll
            for (int r = 0; r < 16; r++) {
                int kr = (r & 3) + 8 * (r >> 2) + h4;
                float skx = sqAll[(size_t)(k0 + kr) * 4];
                float sE = fmaxf(fmaf(-2.f, aE[r], sqqxE + skx), EPSf);
                float dE = __builtin_amdgcn_sqrtf(sE);
                float cv = aS[r];
                float ax = fminf(fabsf(cv), 1.f - EPSf);
                float sq1 = __builtin_amdgcn_sqrtf(1.f - ax);
                float pa = sq1 * fmaf(ax, fmaf(ax, fmaf(ax, -0.0187293f, 0.0742610f), -0.2121144f), 1.5707288f);
                float dS = (cv < 0.f) ? (3.14159265f - pa) : pa;
                p[r] = fmaf(al2, dE, be2 * dS);
            }
        }

        {
            __builtin_amdgcn_s_setprio(1);
            f16v aH = {}, aF = {};
            #pragma unroll
            for (int c = 8; c < 20; c++) {
                s8v a = *(const s8v*)(kp + c * 1024);
                s8v q = *(const s8v*)(qlds + c * 1024 + laneoff);
                if (c < 12) aH = MFMA32x32(a, q, aH);
                else        aF = MFMA32x32(a, q, aF);
            }
            __builtin_amdgcn_s_setprio(0);
            #pragma unroll
            for (int r = 0; r < 16; r++) {
                int kr = (r & 3) + 8 * (r >> 2) + h4;
                const float4 sk = *(const float4*)(sqAll + (size_t)(k0 + kr) * 4);
                float d2 = fmaxf(fmaf(-2.f, aH[r], sqqy + sk.y), 0.f);
                float den = fmaf(sqqz, sk.z, EPSf);
                float arx = fmaxf(fmaf(d2 + d2, __builtin_amdgcn_rcpf(den), 1.f), 1.f + EPSf);
                float sh = __builtin_amdgcn_sqrtf(fmaf(arx, arx, -1.f));
                float lH = log2f(arx + sh);
                float sF = fmaxf(fmaf(-2.f, aF[r], sqqwE + sk.w), EPSf);
                float dF = __builtin_amdgcn_sqrtf(sF);
                p[r] = fmaf(de2, dF, fmaf(gl2, lH, p[r]));
            }
        }

        const char* vp = vtb + (size_t)kblk * 4096 + laneoff;
        s8v b00 = *(const s8v*)(vp);
        s8v b01 = *(const s8v*)(vp + 1024);
        s8v b10 = *(const s8v*)(vp + 2048);
        s8v b11 = *(const s8v*)(vp + 3072);

        float mt = p[0];
        #pragma unroll
        for (int r = 1; r < 16; r++) mt = fmaxf(mt, p[r]);
        mt = fmaxf(mt, __shfl_xor(mt, 32, 64));
        if (!__all(mt <= m_run + 8.f)) {
            float mnew = fmaxf(m_run, mt);
            float sc = exp2f(m_run - mnew);
            l_run *= sc;
            m_run = mnew;
            #pragma unroll
            for (int r = 0; r < 16; r++) {
                float s = __shfl(sc, (r & 3) + 8 * (r >> 2) + h4, 64);
                o0[r] *= s; o1[r] *= s;
            }
        }
        float ps = 0.f;
        #pragma unroll
        for (int r = 0; r < 16; r++) { p[r] = exp2f(p[r] - m_run); ps += p[r]; }
        ps += __shfl_xor(ps, 32, 64);
        l_run += ps;

        unsigned int w0, w1, w2, w3, y0, y1, y2, y3;
        PKB(w0, p[0], p[1]);   PKB(w1, p[2], p[3]);
        PKB(w2, p[4], p[5]);   PKB(w3, p[6], p[7]);
        PKB(y0, p[8], p[9]);   PKB(y1, p[10], p[11]);
        PKB(y2, p[12], p[13]); PKB(y3, p[14], p[15]);
        SWL(w0, w2); SWL(w1, w3); SWL(y0, y2); SWL(y1, y3);
        int4 t1; t1.x = (int)w0; t1.y = (int)w1; t1.z = (int)w2; t1.w = (int)w3;
        int4 t2; t2.x = (int)y0; t2.y = (int)y1; t2.z = (int)y2; t2.w = (int)y3;
        s8v A1 = *(s8v*)&t1;
        s8v A2 = *(s8v*)&t2;

        __builtin_amdgcn_s_setprio(1);
        o0 = MFMA32x32(A1, b00, o0);
        o0 = MFMA32x32(A2, b10, o0);
        o1 = MFMA32x32(A1, b01, o1);
        o1 = MFMA32x32(A2, b11, o1);
        __builtin_amdgcn_s_setprio(0);
    }

    float* slotO0 = (float*)sm;
    float* slotO1 = (float*)(sm + 8192);
    float* slotM0 = (float*)(sm + 16384);
    float* slotM1 = (float*)(sm + 16896);

    __syncthreads();
    if (par >= 2) {
        float* so = (par == 2) ? slotO0 : slotO1;
        float* sM = (par == 2) ? slotM0 : slotM1;
        #pragma unroll
        for (int r = 0; r < 16; r++) {
            int qr = (r & 3) + 8 * (r >> 2) + h4;
            so[qr * 64 + l31] = o0[r];
            so[qr * 64 + 32 + l31] = o1[r];
        }
        if (lane < 32) { sM[lane] = m_run; sM[32 + lane] = l_run; }
    }
    __syncthreads();
    if (par < 2) {
        float* so = (par == 0) ? slotO0 : slotO1;
        float* sM = (par == 0) ? slotM0 : slotM1;
        float m2 = sM[l31], l2 = sM[32 + l31];
        float M = fmaxf(m_run, m2);
        float s1 = exp2f(m_run - M), s2 = exp2f(m2 - M);
        l_run = l_run * s1 + l2 * s2;
        m_run = M;
        #pragma unroll
        for (int r = 0; r < 16; r++) {
            int qr = (r & 3) + 8 * (r >> 2) + h4;
            float a = __shfl(s1, qr, 64), b = __shfl(s2, qr, 64);
            o0[r] = o0[r] * a + so[qr * 64 + l31] * b;
            o1[r] = o1[r] * a + so[qr * 64 + 32 + l31] * b;
        }
    }
    __syncthreads();
    if (par == 1) {
        #pragma unroll
        for (int r = 0; r < 16; r++) {
            int qr = (r & 3) + 8 * (r >> 2) + h4;
            slotO0[qr * 64 + l31] = o0[r];
            slotO0[qr * 64 + 32 + l31] = o1[r];
        }
        if (lane < 32) { slotM0[lane] = m_run; slotM0[32 + lane] = l_run; }
    }
    __syncthreads();
    if (par == 0) {
        float m2 = slotM0[l31], l2 = slotM0[32 + l31];
        float M = fmaxf(m_run, m2);
        float s1 = exp2f(m_run - M), s2 = exp2f(m2 - M);
        float lt = l_run * s1 + l2 * s2;
        float inv = 1.f / lt;
        float a0 = s1 * inv, b0 = s2 * inv;
        #pragma unroll
        for (int r = 0; r < 16; r++) {
            int qr = (r & 3) + 8 * (r >> 2) + h4;
            float a = __shfl(a0, qr, 64), b = __shfl(b0, qr, 64);
            float r0 = o0[r] * a + slotO0[qr * 64 + l31] * b;
            float r1 = o1[r] * a + slotO0[qr * 64 + 32 + l31] * b;
            size_t row = (size_t)bz * Nd + q0 + qr;
            aout[row * Dd + hh * 64 + l31] = __float2bfloat16(r0);
            aout[row * Dd + hh * 64 + 32 + l31] = __float2bfloat16(r1);
        }
    }
}

extern "C" void kernel_launch(void* const* d_in, const int* in_sizes, int n_in,
                              void* d_out, int out_size, void* d_ws, size_t ws_size,
                              hipStream_t stream) {
    const float* x    = (const float*)d_in[0];
    const int*   mask = (const int*)d_in[1];
    const float* WE   = (const float*)d_in[2];
    const float* bE   = (const float*)d_in[3];
    const float* WS   = (const float*)d_in[4];
    const float* bS   = (const float*)d_in[5];
    const float* WH   = (const float*)d_in[6];
    const float* bH   = (const float*)d_in[7];
    const float* Wrff = (const float*)d_in[8];
    const float* brff = (const float*)d_in[9];
    const float* alpha = (const float*)d_in[10];
    const float* beta  = (const float*)d_in[11];
    const float* gamma_ = (const float*)d_in[12];
    const float* delta = (const float*)d_in[13];
    const float* temperature = (const float*)d_in[14];
    const float* Wv = (const float*)d_in[15];
    const float* bv = (const float*)d_in[16];
    const float* Wo = (const float*)d_in[17];
    const float* bo = (const float*)d_in[18];

    char* ws = (char*)d_ws;
    unsigned short* wit = (unsigned short*)ws;               // 32768*320*2 = 20971520
    float* sq  = (float*)(ws + 20971520);                    // 524288
    unsigned short* xb  = (unsigned short*)(ws + 21495808);  // 4194304
    unsigned short* wvb = (unsigned short*)(ws + 25690112);  // 2097152
    unsigned short* wob = (unsigned short*)(ws + 27787264);  // 2097152 (contiguous after wvb)
    unsigned short* vt  = (unsigned short*)(ws + 29884416);  // 4194304
    __hip_bfloat16* aout = (__hip_bfloat16*)(ws + 34078720); // 4194304
    // W-frag buffers live in the aout region: dead until attn overwrites them
    // (last read of wfH/wfL is in witness_kernel, before attn runs).
    unsigned short* wfH = (unsigned short*)(ws + 34078720);            // 655360 B
    unsigned short* wfL = (unsigned short*)(ws + 34078720 + 655360);   // 655360 B

    prep_kernel<<<dim3(2208), 256, 0, stream>>>(Wv, Wo, wvb, WE, WS, WH, Wrff, wfH, wfL);

    witness_kernel<<<dim3(8, 16, 2), 256, 0, stream>>>(
        x, mask, bE, bS, bH, brff, wfH, wfL, wit, sq, xb);

    gemm_bf16_kernel<1><<<dim3(16, 32), 256, 0, stream>>>(xb, wvb, bv, nullptr, vt);

    attn_kernel<<<dim3(1024), 256, 0, stream>>>(
        wit, sq, vt, alpha, beta, gamma_, delta, temperature, aout);

    gemm_bf16_kernel<0><<<dim3(16, 32), 256, 0, stream>>>(
        (const unsigned short*)aout, wob, bo, (float*)d_out, nullptr);
}